// Round 12
// baseline (365.972 us; speedup 1.0000x reference)
//
#include <hip/hip_runtime.h>
#include <math.h>

#define N_NODES 50000
#define E_RAW   1600000
#define TE      (E_RAW + N_NODES)     // 1650000 edges incl. self loops
#define TEP     (TE + 8 * N_NODES)    // CSR padded to 8-aligned rows (upper bound)
#define F_IN    128
#define H1      4
#define F1      128                   // H1*C1
#define F2      64
#define NEG_SLOPE 0.2f
#define EPS_F   1e-16f

// ---- bucket-sort CSR build params (all atomics are LDS-scope) ----
#define NBINS   196                   // coarse buckets: dst >> 8 (50000/256)
#define NBLK_A  128                   // blocks in coarse hist/scatter
#define EPB     ((TE + NBLK_A - 1) / NBLK_A)   // edges per block = 12891
#define MM_BLOCKS (N_NODES / 16)      // 3125

__device__ __forceinline__ float lrelu(float v) { return v > 0.f ? v : NEG_SLOPE * v; }

typedef float vf2 __attribute__((ext_vector_type(2)));

// bf16 round-to-nearest-even pack/unpack
__device__ __forceinline__ unsigned short f2bf(float f) {
    unsigned u = __float_as_uint(f);
    return (unsigned short)((u + 0x7fffu + ((u >> 16) & 1u)) >> 16);
}
__device__ __forceinline__ float bf2f(unsigned short s) {
    return __uint_as_float(((unsigned)s) << 16);
}
// fp8 OCP e4m3 via gfx950 HW cvt
__device__ __forceinline__ unsigned char f2fp8(float f) {
    int p = __builtin_amdgcn_cvt_pk_fp8_f32(f, f, 0, false);
    return (unsigned char)(p & 0xff);
}
__device__ __forceinline__ vf2 fp8pair2f(int u) {     // low 2 bytes -> 2 floats
    return __builtin_amdgcn_cvt_pk_f32_fp8(u, false);
}

// ---------------- layer1 matmul (+ fused coarse histogram) ----------------
// Blocks [0,3125): mm, 16 nodes/block, c=t&127, p=t>>7. W1 staged in LDS in two
// 64-row halves (in-loop GLOBAL W loads were the round-11 bottleneck: 128
// L2-latency-bound loads/thread, VALUBusy 50%, occ 28%). xw stored fp8 e4m3;
// attention coefs fp32-exact from registers. #pragma unroll 2: VGPR cliff (r4).
// Blocks [3125, 3125+NBLK_A): coarse dst-histogram (independent work, overlaps).
__global__ __launch_bounds__(256) void k_l1_mm_hist(
    const float* __restrict__ x, const float* __restrict__ W,
    const float* __restrict__ atts, const float* __restrict__ attd,
    unsigned char* __restrict__ xwf8, float* __restrict__ a1s, float* __restrict__ a1d,
    const int* __restrict__ ei, int* __restrict__ cnt) {
    __shared__ __align__(16) float wls[64 * F1];    // 32 KB: one K-half of W1
    __shared__ __align__(16) float xs[16][F_IN];    // 8 KB
    const int t = threadIdx.x;
    if (blockIdx.x >= MM_BLOCKS) {
        // ---- coarse histogram part (LDS atomics only) ----
        int* hist = (int*)&xs[0][0];
        const int blk = blockIdx.x - MM_BLOCKS;
        for (int i = t; i < NBINS; i += 256) hist[i] = 0;
        __syncthreads();
        const int e0 = blk * EPB, e1 = min(TE, e0 + EPB);
        for (int e = e0 + t; e < e1; e += 256) {
            int d = (e < E_RAW) ? ei[E_RAW + e] : (e - E_RAW);
            atomicAdd(&hist[d >> 8], 1);
        }
        __syncthreads();
        for (int i = t; i < NBINS; i += 256) cnt[i * NBLK_A + blk] = hist[i];
        return;
    }
    const int c = t & 127;
    const int p = t >> 7;
    const int n0 = blockIdx.x * 16;
    {
        const float4* src = (const float4*)(x + (size_t)n0 * F_IN);
        float4* dstv = (float4*)&xs[0][0];
        dstv[t] = src[t];
        dstv[t + 256] = src[t + 256];
    }
    float acc[8];
#pragma unroll
    for (int j = 0; j < 8; ++j) acc[j] = 0.f;
    const float* xsp = &xs[p * 8][0];
#pragma unroll
    for (int half = 0; half < 2; ++half) {
        __syncthreads();   // first pass: covers xs staging; later: protect wls reuse
        {   // stage 64 W rows = 8192 floats = 2048 float4, 8 per thread
            const float4* wsrc = (const float4*)(W + (size_t)half * 64 * F1);
            float4* wdst = (float4*)wls;
#pragma unroll
            for (int i = 0; i < 8; ++i) wdst[t + 256 * i] = wsrc[t + 256 * i];
        }
        __syncthreads();
#pragma unroll 2
        for (int k4 = 0; k4 < 16; ++k4) {
            int k = k4 * 4;
            float w0 = wls[(k + 0) * F1 + c];
            float w1 = wls[(k + 1) * F1 + c];
            float w2 = wls[(k + 2) * F1 + c];
            float w3 = wls[(k + 3) * F1 + c];
#pragma unroll
            for (int j = 0; j < 8; ++j) {
                float4 xv = ((const float4*)(xsp + j * F_IN))[half * 16 + k4];
                acc[j] = fmaf(xv.x, w0, fmaf(xv.y, w1, fmaf(xv.z, w2, fmaf(xv.w, w3, acc[j]))));
            }
        }
    }
    float ats = atts[c], atd = attd[c];
#pragma unroll
    for (int j = 0; j < 8; ++j) {
        int n = n0 + p * 8 + j;
        xwf8[(size_t)n * F1 + c] = f2fp8(acc[j]);
        float ps = acc[j] * ats, pd = acc[j] * atd;
#pragma unroll
        for (int off = 16; off; off >>= 1) {
            ps += __shfl_down(ps, off, 32);
            pd += __shfl_down(pd, off, 32);
        }
        if ((t & 31) == 0) {
            int h = (c >> 5);
            a1s[n * H1 + h] = ps;
            a1d[n * H1 + h] = pd;
        }
    }
}

// ---------------- per-bin scan of cnt across blocks + bin totals -------------
__global__ __launch_bounds__(64) void k_btot(int* __restrict__ cnt, int* __restrict__ btot) {
    const int bin = blockIdx.x, lane = threadIdx.x;
    int c0 = cnt[bin * NBLK_A + 2 * lane];
    int c1 = cnt[bin * NBLK_A + 2 * lane + 1];
    int s = c0 + c1;
    int incl = s;
#pragma unroll
    for (int off = 1; off < 64; off <<= 1) {
        int u = __shfl_up(incl, off, 64);
        if (lane >= off) incl += u;
    }
    int excl = incl - s;
    cnt[bin * NBLK_A + 2 * lane] = excl;
    cnt[bin * NBLK_A + 2 * lane + 1] = excl + c0;
    if (lane == 63) btot[bin] = incl;
}

// ---------------- exclusive scan of 196 bin totals -> bucket_start -----------
__global__ __launch_bounds__(64) void k_bstart(const int* __restrict__ btot,
                                               int* __restrict__ bstart) {
    const int lane = threadIdx.x;
    int v[4]; int s = 0;
#pragma unroll
    for (int j = 0; j < 4; ++j) {
        int i = 4 * lane + j;
        v[j] = (i < NBINS) ? btot[i] : 0;
        s += v[j];
    }
    int incl = s;
#pragma unroll
    for (int off = 1; off < 64; off <<= 1) {
        int u = __shfl_up(incl, off, 64);
        if (lane >= off) incl += u;
    }
    int run = incl - s;
#pragma unroll
    for (int j = 0; j < 4; ++j) {
        int i = 4 * lane + j;
        if (i < NBINS) bstart[i] = run;
        run += v[j];
    }
    if (lane == 63) bstart[NBINS] = TE;
}

// ---------------- scatter into coarse buckets (plain stores; r10 lesson) -----
// payload u32 = (dst&255)<<16 | src   (src < 65536)
__global__ __launch_bounds__(256) void k_scatter_coarse(const int* __restrict__ ei,
                                                        const int* __restrict__ cnt,
                                                        const int* __restrict__ bstart,
                                                        unsigned* __restrict__ cbuf) {
    __shared__ int cur[NBINS];
    const int t = threadIdx.x, blk = blockIdx.x;
    for (int i = t; i < NBINS; i += 256) cur[i] = cnt[i * NBLK_A + blk] + bstart[i];
    __syncthreads();
    const int e0 = blk * EPB, e1 = min(TE, e0 + EPB);
    for (int e = e0 + t; e < e1; e += 256) {
        int s, d;
        if (e < E_RAW) { s = ei[e]; d = ei[E_RAW + e]; }
        else { s = e - E_RAW; d = s; }
        int pos = atomicAdd(&cur[d >> 8], 1);   // LDS atomic
        cbuf[pos] = ((unsigned)(d & 255) << 16) | (unsigned)s;
    }
}

// ---------------- fine histogram -> deg --------------------
__global__ __launch_bounds__(256) void k_fine_hist(const unsigned* __restrict__ cbuf,
                                                   const int* __restrict__ bstart,
                                                   int* __restrict__ deg) {
    __shared__ int hist[256];
    const int t = threadIdx.x, b = blockIdx.x;
    hist[t] = 0;
    __syncthreads();
    const int i0 = bstart[b], i1 = bstart[b + 1];
    for (int i = i0 + t; i < i1; i += 256) atomicAdd(&hist[cbuf[i] >> 16], 1);
    __syncthreads();
    const int d = b * 256 + t;
    if (d < N_NODES) deg[d] = hist[t];
}

// ---------------- exclusive scan over 8-PADDED degrees (2-level) --------------
__global__ __launch_bounds__(1024) void k_scan1(const int* __restrict__ deg,
                                                int* __restrict__ incl, int* __restrict__ bsum) {
    int t = threadIdx.x, g = blockIdx.x;
    int idx = g * 1024 + t;
    int v = (idx < N_NODES) ? ((deg[idx] + 7) & ~7) : 0;
    int lane = t & 63, w = t >> 6;
#pragma unroll
    for (int off = 1; off < 64; off <<= 1) {
        int u = __shfl_up(v, off, 64);
        if (lane >= off) v += u;
    }
    __shared__ int ws[16];
    if (lane == 63) ws[w] = v;
    __syncthreads();
    if (w == 0 && lane < 16) {
        int s = ws[lane];
#pragma unroll
        for (int off = 1; off < 16; off <<= 1) {
            int u = __shfl_up(s, off, 16);
            if (lane >= off) s += u;
        }
        ws[lane] = s;
    }
    __syncthreads();
    if (w > 0) v += ws[w - 1];
    if (idx < N_NODES) incl[idx] = v;
    if (t == 1023) bsum[g] = v;
}

__global__ void k_scan2(int* __restrict__ bsum, int nblk) {
    int t = threadIdx.x;
    int v = (t < nblk) ? bsum[t] : 0;
#pragma unroll
    for (int off = 1; off < 64; off <<= 1) {
        int u = __shfl_up(v, off, 64);
        if (t >= off) v += u;
    }
    if (t < nblk) bsum[t] = v;
}

__global__ __launch_bounds__(1024) void k_scan3(const int* __restrict__ incl,
                                                const int* __restrict__ bsum,
                                                int* __restrict__ rowstart) {
    int idx = blockIdx.x * 1024 + threadIdx.x;
    if (idx >= N_NODES) return;
    int off = (blockIdx.x > 0) ? bsum[blockIdx.x - 1] : 0;
    rowstart[idx + 1] = incl[idx] + off;
    if (idx == 0) rowstart[0] = 0;
}

// ---------------- per-bucket scatter into csr (plain stores) -----------------
__global__ __launch_bounds__(256) void k_build_csr(const unsigned* __restrict__ cbuf,
                                                   const int* __restrict__ bstart,
                                                   const int* __restrict__ rowstart,
                                                   int* __restrict__ csr) {
    __shared__ int cur[256];
    const int t = threadIdx.x, b = blockIdx.x;
    const int d = b * 256 + t;
    cur[t] = (d < N_NODES) ? rowstart[d] : 0;
    __syncthreads();
    const int i0 = bstart[b], i1 = bstart[b + 1];
    for (int i = i0 + t; i < i1; i += 256) {
        unsigned v = cbuf[i];
        int pos = atomicAdd(&cur[v >> 16], 1);   // LDS atomic
        csr[pos] = (int)(v & 0xffffu);
    }
}

// ---------------- layer1 edge weights (bf16 planes) + pad zero-fill ----------
__global__ __launch_bounds__(256) void k_ew1(
    const int* __restrict__ rowstart, int* __restrict__ csr, const int* __restrict__ deg,
    const float* __restrict__ a1s, const float* __restrict__ a1d,
    unsigned short* __restrict__ ew1) {
    const int lane = threadIdx.x & 63;
    const int wid = threadIdx.x >> 6;
    const int n = blockIdx.x * 4 + wid;
    if (n >= N_NODES) return;
    const int rs = rowstart[n];
    const int dg = deg[n];
    const int re = rs + dg;
    const int re8 = rs + ((dg + 7) & ~7);
    const float4 ad = ((const float4*)a1d)[n];
    for (int i = rs + lane; i < re8; i += 64) {
        if (i < re) {
            int s = csr[i];
            float4 as = ((const float4*)a1s)[s];
            ew1[0 * TEP + i] = f2bf(expf(lrelu(as.x + ad.x)));
            ew1[1 * TEP + i] = f2bf(expf(lrelu(as.y + ad.y)));
            ew1[2 * TEP + i] = f2bf(expf(lrelu(as.z + ad.z)));
            ew1[3 * TEP + i] = f2bf(expf(lrelu(as.w + ad.w)));
        } else {
            csr[i] = 0;
            ew1[0 * TEP + i] = 0;
            ew1[1 * TEP + i] = 0;
            ew1[2 * TEP + i] = 0;
            ew1[3 * TEP + i] = 0;
        }
    }
}

// ---------------- layer1 gather: fp8 rows + bf16 weights, 8 edges/iter -------
__global__ __launch_bounds__(256) void k_l1_gather(
    const int* __restrict__ rowstart, const int* __restrict__ csr,
    const int* __restrict__ deg, const unsigned short* __restrict__ ew1,
    const unsigned short* __restrict__ xw8, const float* __restrict__ b1,
    float* __restrict__ h1) {
    const int lane = threadIdx.x & 63;
    const int wid = threadIdx.x >> 6;
    const int n = blockIdx.x * 4 + wid;
    if (n >= N_NODES) return;
    const int rs = rowstart[n];
    const int nb8 = (deg[n] + 7) >> 3;
    const int h = lane >> 4;
    const int4* c4 = (const int4*)(csr + rs);
    const ushort4* w4 = (const ushort4*)(ew1 + h * TEP + rs);
    float den = 0.f, ax = 0.f, ay = 0.f;
    for (int b = 0; b < nb8; ++b) {
        int4 sA = c4[2 * b], sB = c4[2 * b + 1];
        ushort4 wA = w4[2 * b], wB = w4[2 * b + 1];
        int u0 = xw8[sA.x * 64 + lane], u1 = xw8[sA.y * 64 + lane];
        int u2 = xw8[sA.z * 64 + lane], u3 = xw8[sA.w * 64 + lane];
        int u4 = xw8[sB.x * 64 + lane], u5 = xw8[sB.y * 64 + lane];
        int u6 = xw8[sB.z * 64 + lane], u7 = xw8[sB.w * 64 + lane];
        vf2 v0 = fp8pair2f(u0), v1 = fp8pair2f(u1), v2 = fp8pair2f(u2), v3 = fp8pair2f(u3);
        vf2 v4 = fp8pair2f(u4), v5 = fp8pair2f(u5), v6 = fp8pair2f(u6), v7 = fp8pair2f(u7);
        float wa0 = bf2f(wA.x), wa1 = bf2f(wA.y), wa2 = bf2f(wA.z), wa3 = bf2f(wA.w);
        float wb0 = bf2f(wB.x), wb1 = bf2f(wB.y), wb2 = bf2f(wB.z), wb3 = bf2f(wB.w);
        den += ((wa0 + wa1) + (wa2 + wa3)) + ((wb0 + wb1) + (wb2 + wb3));
        ax = fmaf(wa0, v0.x, fmaf(wa1, v1.x, fmaf(wa2, v2.x, fmaf(wa3, v3.x, ax))));
        ay = fmaf(wa0, v0.y, fmaf(wa1, v1.y, fmaf(wa2, v2.y, fmaf(wa3, v3.y, ay))));
        ax = fmaf(wb0, v4.x, fmaf(wb1, v5.x, fmaf(wb2, v6.x, fmaf(wb3, v7.x, ax))));
        ay = fmaf(wb0, v4.y, fmaf(wb1, v5.y, fmaf(wb2, v6.y, fmaf(wb3, v7.y, ay))));
    }
    const float inv = 1.f / (den + EPS_F);
    const int c0 = 2 * lane;
    float o0 = fmaf(ax, inv, b1[c0]);
    float o1 = fmaf(ay, inv, b1[c0 + 1]);
    o0 = o0 > 0.f ? o0 : expm1f(o0);
    o1 = o1 > 0.f ? o1 : expm1f(o1);
    ((float2*)h1)[(size_t)n * 64 + lane] = make_float2(o0, o1);
}

// ---------------- layer2 matmul + attention coefs (fp8 xw2, W2 in LDS) -------
__global__ __launch_bounds__(256) void k_l2_mm(
    const float* __restrict__ h1, const float* __restrict__ W,
    const float* __restrict__ atts, const float* __restrict__ attd,
    unsigned char* __restrict__ xwf8, float* __restrict__ a2s, float* __restrict__ a2d) {
    __shared__ __align__(16) float wls[F1 * F2];    // 32 KB: whole W2
    __shared__ __align__(16) float xs[16][F1];      // 8 KB
    const int t = threadIdx.x;
    const int c = t & 63;
    const int p = t >> 6;
    const int n0 = blockIdx.x * 16;
    {
        const float4* src = (const float4*)(h1 + (size_t)n0 * F1);
        float4* dstv = (float4*)&xs[0][0];
        dstv[t] = src[t];
        dstv[t + 256] = src[t + 256];
        const float4* wsrc = (const float4*)W;
        float4* wdst = (float4*)wls;
#pragma unroll
        for (int i = 0; i < 8; ++i) wdst[t + 256 * i] = wsrc[t + 256 * i];
    }
    __syncthreads();
    float acc[4];
#pragma unroll
    for (int j = 0; j < 4; ++j) acc[j] = 0.f;
    const float* xsp = &xs[p * 4][0];
#pragma unroll 2
    for (int k4 = 0; k4 < F1 / 4; ++k4) {
        int k = k4 * 4;
        float w0 = wls[(k + 0) * F2 + c];
        float w1 = wls[(k + 1) * F2 + c];
        float w2 = wls[(k + 2) * F2 + c];
        float w3 = wls[(k + 3) * F2 + c];
#pragma unroll
        for (int j = 0; j < 4; ++j) {
            float4 xv = ((const float4*)(xsp + j * F1))[k4];
            acc[j] = fmaf(xv.x, w0, fmaf(xv.y, w1, fmaf(xv.z, w2, fmaf(xv.w, w3, acc[j]))));
        }
    }
    float ats = atts[c], atd = attd[c];
#pragma unroll
    for (int j = 0; j < 4; ++j) {
        int n = n0 + p * 4 + j;
        xwf8[(size_t)n * F2 + c] = f2fp8(acc[j]);
        float ps = acc[j] * ats, pd = acc[j] * atd;
#pragma unroll
        for (int off = 32; off; off >>= 1) {
            ps += __shfl_down(ps, off, 64);
            pd += __shfl_down(pd, off, 64);
        }
        if (c == 0) { a2s[n] = ps; a2d[n] = pd; }
    }
}

// ---------------- layer2 edge weights (bf16) ----------------
__global__ __launch_bounds__(256) void k_ew2(
    const int* __restrict__ rowstart, const int* __restrict__ csr,
    const int* __restrict__ deg,
    const float* __restrict__ a2s, const float* __restrict__ a2d,
    unsigned short* __restrict__ ew2) {
    const int lane = threadIdx.x & 63;
    const int wid = threadIdx.x >> 6;
    const int n = blockIdx.x * 4 + wid;
    if (n >= N_NODES) return;
    const int rs = rowstart[n];
    const int dg = deg[n];
    const int re = rs + dg;
    const int re8 = rs + ((dg + 7) & ~7);
    const float adv = a2d[n];
    for (int i = rs + lane; i < re8; i += 64) {
        if (i < re) {
            int s = csr[i];
            ew2[i] = f2bf(expf(lrelu(a2s[s] + adv)));
        } else {
            ew2[i] = 0;
        }
    }
}

// ---------------- layer2 gather: fp8 rows + bf16 weights ---------------------
__global__ __launch_bounds__(256) void k_l2_gather(
    const int* __restrict__ rowstart, const int* __restrict__ csr,
    const int* __restrict__ deg, const unsigned short* __restrict__ ew2,
    const unsigned char* __restrict__ xw8, float* __restrict__ h2) {
    const int lane = threadIdx.x & 63;
    const int wid = threadIdx.x >> 6;
    const int n = blockIdx.x * 4 + wid;
    if (n >= N_NODES) return;
    const int rs = rowstart[n];
    const int nb8 = (deg[n] + 7) >> 3;
    const int4* c4 = (const int4*)(csr + rs);
    const ushort4* w4 = (const ushort4*)(ew2 + rs);
    float den = 0.f, acc = 0.f;
    for (int b = 0; b < nb8; ++b) {
        int4 sA = c4[2 * b], sB = c4[2 * b + 1];
        ushort4 wA = w4[2 * b], wB = w4[2 * b + 1];
        int u0 = xw8[(size_t)sA.x * F2 + lane], u1 = xw8[(size_t)sA.y * F2 + lane];
        int u2 = xw8[(size_t)sA.z * F2 + lane], u3 = xw8[(size_t)sA.w * F2 + lane];
        int u4 = xw8[(size_t)sB.x * F2 + lane], u5 = xw8[(size_t)sB.y * F2 + lane];
        int u6 = xw8[(size_t)sB.z * F2 + lane], u7 = xw8[(size_t)sB.w * F2 + lane];
        float v0 = fp8pair2f(u0).x, v1 = fp8pair2f(u1).x;
        float v2 = fp8pair2f(u2).x, v3 = fp8pair2f(u3).x;
        float v4 = fp8pair2f(u4).x, v5 = fp8pair2f(u5).x;
        float v6 = fp8pair2f(u6).x, v7 = fp8pair2f(u7).x;
        float wa0 = bf2f(wA.x), wa1 = bf2f(wA.y), wa2 = bf2f(wA.z), wa3 = bf2f(wA.w);
        float wb0 = bf2f(wB.x), wb1 = bf2f(wB.y), wb2 = bf2f(wB.z), wb3 = bf2f(wB.w);
        den += ((wa0 + wa1) + (wa2 + wa3)) + ((wb0 + wb1) + (wb2 + wb3));
        acc = fmaf(wa0, v0, fmaf(wa1, v1, fmaf(wa2, v2, fmaf(wa3, v3, acc))));
        acc = fmaf(wb0, v4, fmaf(wb1, v5, fmaf(wb2, v6, fmaf(wb3, v7, acc))));
    }
    h2[(size_t)n * F2 + lane] = acc / (den + EPS_F);
}

// ---------------- mean over nodes (fp64 accum) ----------------
#define MEAN_BLOCKS 256
__global__ __launch_bounds__(256) void k_mean(const float* __restrict__ h2,
                                              double* __restrict__ accum) {
    const int t = threadIdx.x;
    const int c = t & 63;
    double acc = 0.0;
    const size_t total = (size_t)N_NODES * F2;
    for (size_t idx = (size_t)blockIdx.x * 256 + t; idx < total; idx += (size_t)MEAN_BLOCKS * 256)
        acc += (double)h2[idx];
    __shared__ double red[256];
    red[t] = acc;
    __syncthreads();
    if (t < 64) {
        double v = red[t] + red[t + 64] + red[t + 128] + red[t + 192];
        atomicAdd(&accum[c], v);
    }
}

__global__ void k_final(const double* __restrict__ accum, const float* __restrict__ b2,
                        float* __restrict__ out) {
    int t = threadIdx.x;
    if (t < F2) out[t] = (float)(accum[t] * (1.0 / (double)N_NODES)) + b2[t];
}

// ---------------- launch ----------------
extern "C" void kernel_launch(void* const* d_in, const int* in_sizes, int n_in,
                              void* d_out, int out_size, void* d_ws, size_t ws_size,
                              hipStream_t stream) {
    (void)in_sizes; (void)n_in; (void)out_size; (void)ws_size;
    const float* x   = (const float*)d_in[0];
    const int*   ei  = (const int*)d_in[1];
    const float* W1  = (const float*)d_in[2];
    const float* as1 = (const float*)d_in[3];
    const float* ad1 = (const float*)d_in[4];
    const float* b1  = (const float*)d_in[5];
    const float* W2  = (const float*)d_in[6];
    const float* as2 = (const float*)d_in[7];
    const float* ad2 = (const float*)d_in[8];
    const float* b2  = (const float*)d_in[9];
    float* out = (float*)d_out;

    char* ws = (char*)d_ws;
    size_t off = 0;
    auto alloc = [&](size_t bytes) -> void* {
        void* p = ws + off;
        off += (bytes + 255) & ~(size_t)255;
        return p;
    };
    unsigned char*  xw1f8 = (unsigned char*)alloc((size_t)N_NODES * F1);
    float* h1       = (float*)alloc((size_t)N_NODES * F1 * 4);
    unsigned char*  xw2f8 = (unsigned char*)alloc((size_t)N_NODES * F2);
    float* h2       = (float*)alloc((size_t)N_NODES * F2 * 4);
    unsigned short* ew1 = (unsigned short*)alloc((size_t)H1 * TEP * 2);
    unsigned short* ew2 = (unsigned short*)alloc((size_t)TEP * 2);
    float* a1s      = (float*)alloc((size_t)N_NODES * H1 * 4);
    float* a1d      = (float*)alloc((size_t)N_NODES * H1 * 4);
    float* a2s      = (float*)alloc((size_t)N_NODES * 4);
    float* a2d      = (float*)alloc((size_t)N_NODES * 4);
    int*   deg      = (int*)alloc((size_t)N_NODES * 4);
    unsigned* cbuf  = (unsigned*)alloc((size_t)TE * 4);
    int*   cnt      = (int*)alloc((size_t)NBINS * NBLK_A * 4);
    int*   btot     = (int*)alloc((size_t)NBINS * 4);
    int*   bstart   = (int*)alloc((size_t)(NBINS + 1) * 4);
    int*   rowstart = (int*)alloc((size_t)(N_NODES + 1) * 4);
    int*   csr      = (int*)alloc((size_t)TEP * 4);
    int*   incl     = (int*)alloc((size_t)N_NODES * 4);
    int*   bsum     = (int*)alloc(64 * 4);
    double* accum   = (double*)alloc(F2 * 8);

    const int nscan = (N_NODES + 1023) / 1024;  // 49
    const int nwave4 = (N_NODES + 3) / 4;       // 12500

    hipMemsetAsync(accum, 0, F2 * 8, stream);
    k_l1_mm_hist<<<MM_BLOCKS + NBLK_A, 256, 0, stream>>>(x, W1, as1, ad1, xw1f8, a1s, a1d, ei, cnt);
    k_btot<<<NBINS, 64, 0, stream>>>(cnt, btot);
    k_bstart<<<1, 64, 0, stream>>>(btot, bstart);
    k_scatter_coarse<<<NBLK_A, 256, 0, stream>>>(ei, cnt, bstart, cbuf);
    k_fine_hist<<<NBINS, 256, 0, stream>>>(cbuf, bstart, deg);
    k_scan1<<<nscan, 1024, 0, stream>>>(deg, incl, bsum);
    k_scan2<<<1, 64, 0, stream>>>(bsum, nscan);
    k_scan3<<<nscan, 1024, 0, stream>>>(incl, bsum, rowstart);
    k_build_csr<<<NBINS, 256, 0, stream>>>(cbuf, bstart, rowstart, csr);
    k_ew1<<<nwave4, 256, 0, stream>>>(rowstart, csr, deg, a1s, a1d, ew1);
    k_l1_gather<<<nwave4, 256, 0, stream>>>(rowstart, csr, deg, ew1,
                                            (const unsigned short*)xw1f8, b1, h1);
    k_l2_mm<<<MM_BLOCKS, 256, 0, stream>>>(h1, W2, as2, ad2, xw2f8, a2s, a2d);
    k_ew2<<<nwave4, 256, 0, stream>>>(rowstart, csr, deg, a2s, a2d, ew2);
    k_l2_gather<<<nwave4, 256, 0, stream>>>(rowstart, csr, deg, ew2, xw2f8, h2);
    k_mean<<<MEAN_BLOCKS, 256, 0, stream>>>(h2, accum);
    k_final<<<1, 64, 0, stream>>>(accum, b2, out);
}

// Round 13
// 314.046 us; speedup vs baseline: 1.1653x; 1.1653x over previous
//
#include <hip/hip_runtime.h>
#include <math.h>

#define N_NODES 50000
#define E_RAW   1600000
#define TE      (E_RAW + N_NODES)     // 1650000 edges incl. self loops
#define TEP     (TE + 8 * N_NODES)    // CSR padded to 8-aligned rows (upper bound)
#define F_IN    128
#define H1      4
#define F1      128                   // H1*C1
#define F2      64
#define NEG_SLOPE 0.2f
#define EPS_F   1e-16f
#define XPAD    136                   // LDS row stride in bf16: 128+8 kills the
                                      // 256B-stride 16-way bank conflict (G4)

// ---- bucket-sort CSR build params (all atomics are LDS-scope) ----
#define NBINS   196                   // coarse buckets: dst >> 8 (50000/256)
#define NBLK_A  128                   // blocks in coarse hist/scatter
#define EPB     ((TE + NBLK_A - 1) / NBLK_A)   // edges per block = 12891
#define MM_BLOCKS (N_NODES / 16)      // 3125

__device__ __forceinline__ float lrelu(float v) { return v > 0.f ? v : NEG_SLOPE * v; }

typedef float vf2 __attribute__((ext_vector_type(2)));
typedef short short8 __attribute__((ext_vector_type(8)));
typedef float f32x4 __attribute__((ext_vector_type(4)));

// bf16 round-to-nearest-even pack/unpack
__device__ __forceinline__ unsigned short f2bf(float f) {
    unsigned u = __float_as_uint(f);
    return (unsigned short)((u + 0x7fffu + ((u >> 16) & 1u)) >> 16);
}
__device__ __forceinline__ float bf2f(unsigned short s) {
    return __uint_as_float(((unsigned)s) << 16);
}
// fp8 OCP e4m3 via gfx950 HW cvt
__device__ __forceinline__ unsigned char f2fp8(float f) {
    int p = __builtin_amdgcn_cvt_pk_fp8_f32(f, f, 0, false);
    return (unsigned char)(p & 0xff);
}
__device__ __forceinline__ vf2 fp8pair2f(int u) {     // low 2 bytes -> 2 floats
    return __builtin_amdgcn_cvt_pk_f32_fp8(u, false);
}

// ---------------- prep: W1,W2 -> transposed bf16 [c][k] ----------------
// B-fragments then read 8 contiguous k per lane (one ds_read_b128).
__global__ __launch_bounds__(256) void k_prep(const float* __restrict__ W1,
                                              const float* __restrict__ W2,
                                              unsigned short* __restrict__ w1t,
                                              unsigned short* __restrict__ w2t) {
    int idx = blockIdx.x * 256 + threadIdx.x;   // 96 blocks: 16384 + 8192
    if (idx < 16384) {
        int c = idx >> 7, k = idx & 127;
        w1t[idx] = f2bf(W1[k * F1 + c]);
    } else {
        int j = idx - 16384;
        int c = j >> 7, k = j & 127;
        w2t[j] = f2bf(W2[k * F2 + c]);
    }
}

// ---------------- layer1 matmul via MFMA (+ fused coarse histogram) ----------
// Round-12 lesson: fp32 vector-ALU mm is issue-bound (~2cy/FMA + overhead);
// staging tweaks just move the bottleneck. MFMA offloads the FLOPs entirely.
// Blocks [0,3125): 16 nodes/block, 4 waves; wave w computes channels
// [32w,32w+32) = exactly head w, as 2 16x16 C-tiles over K=128 (4 MFMA each).
// x tile cvt'd to bf16 in LDS (A-frag: m=lane&15, k=quad*8+j); W1t bf16 [c][k]
// staged to LDS (B-frag: n=lane&15 row, 8 contiguous k). C: row(node)=quad*4+reg,
// col(ch)=lane&15. Attention coefs reduce within a quad (16 lanes = 16 ch).
// Blocks [3125,3125+NBLK_A): coarse dst-histogram (independent, overlaps).
__global__ __launch_bounds__(256) void k_l1_mm_hist(
    const float* __restrict__ x, const unsigned short* __restrict__ w1t,
    const float* __restrict__ atts, const float* __restrict__ attd,
    unsigned char* __restrict__ xwf8, float* __restrict__ a1s, float* __restrict__ a1d,
    const int* __restrict__ ei, int* __restrict__ cnt) {
    __shared__ __align__(16) unsigned short wls[F1 * XPAD];   // 34816 B
    __shared__ __align__(16) unsigned short xs[16 * XPAD];    // 4352 B
    const int t = threadIdx.x;
    if (blockIdx.x >= MM_BLOCKS) {
        int* hist = (int*)wls;
        const int blk = blockIdx.x - MM_BLOCKS;
        for (int i = t; i < NBINS; i += 256) hist[i] = 0;
        __syncthreads();
        const int e0 = blk * EPB, e1 = min(TE, e0 + EPB);
        for (int e = e0 + t; e < e1; e += 256) {
            int d = (e < E_RAW) ? ei[E_RAW + e] : (e - E_RAW);
            atomicAdd(&hist[d >> 8], 1);
        }
        __syncthreads();
        for (int i = t; i < NBINS; i += 256) cnt[i * NBLK_A + blk] = hist[i];
        return;
    }
    const int n0 = blockIdx.x * 16;
    {   // stage x tile -> bf16 LDS (padded rows)
        const float4* src = (const float4*)(x + (size_t)n0 * F_IN);
#pragma unroll
        for (int i = 0; i < 2; ++i) {
            int idx = t + 256 * i;              // 0..511
            float4 v = src[idx];
            int row = idx >> 5;
            int col = (idx & 31) * 4;
            ushort4 o = { f2bf(v.x), f2bf(v.y), f2bf(v.z), f2bf(v.w) };
            *(ushort4*)(xs + row * XPAD + col) = o;
        }
        // stage W1t (already bf16) -> LDS padded
        const uint4* wsrc = (const uint4*)w1t;  // 2048 uint4
#pragma unroll
        for (int i = 0; i < 8; ++i) {
            int idx = t + 256 * i;
            uint4 v = wsrc[idx];
            int row = idx >> 4;
            int col = (idx & 15) * 8;
            *(uint4*)(wls + row * XPAD + col) = v;
        }
    }
    __syncthreads();
    const int w = t >> 6;         // wave = head
    const int lane = t & 63;
    const int quad = lane >> 4;
    const int ncol = lane & 15;
    const int ch0 = w * 32;
    const unsigned short* arow = xs + ncol * XPAD;
    const unsigned short* brow0 = wls + (ch0 + ncol) * XPAD;
    const unsigned short* brow1 = brow0 + 16 * XPAD;
    f32x4 acc0 = {0.f, 0.f, 0.f, 0.f}, acc1 = {0.f, 0.f, 0.f, 0.f};
#pragma unroll
    for (int s = 0; s < 4; ++s) {
        int kb = s * 32 + quad * 8;
        short8 a  = *(const short8*)(arow + kb);
        short8 b0 = *(const short8*)(brow0 + kb);
        short8 b1 = *(const short8*)(brow1 + kb);
        acc0 = __builtin_amdgcn_mfma_f32_16x16x32_bf16(a, b0, acc0, 0, 0, 0);
        acc1 = __builtin_amdgcn_mfma_f32_16x16x32_bf16(a, b1, acc1, 0, 0, 0);
    }
    const int ch = ch0 + ncol;
    const float as0 = atts[ch], as1 = atts[ch + 16];
    const float ad0 = attd[ch], ad1 = attd[ch + 16];
#pragma unroll
    for (int reg = 0; reg < 4; ++reg) {
        const int n = n0 + quad * 4 + reg;
        float v0 = acc0[reg], v1 = acc1[reg];
        xwf8[(size_t)n * F1 + ch] = f2fp8(v0);
        xwf8[(size_t)n * F1 + ch + 16] = f2fp8(v1);
        float ps = fmaf(v0, as0, v1 * as1);
        float pd = fmaf(v0, ad0, v1 * ad1);
#pragma unroll
        for (int off = 1; off < 16; off <<= 1) {
            ps += __shfl_xor(ps, off);
            pd += __shfl_xor(pd, off);
        }
        if (ncol == 0) {
            a1s[n * H1 + w] = ps;
            a1d[n * H1 + w] = pd;
        }
    }
}

// ---------------- per-bin scan of cnt across blocks + bin totals -------------
__global__ __launch_bounds__(64) void k_btot(int* __restrict__ cnt, int* __restrict__ btot) {
    const int bin = blockIdx.x, lane = threadIdx.x;
    int c0 = cnt[bin * NBLK_A + 2 * lane];
    int c1 = cnt[bin * NBLK_A + 2 * lane + 1];
    int s = c0 + c1;
    int incl = s;
#pragma unroll
    for (int off = 1; off < 64; off <<= 1) {
        int u = __shfl_up(incl, off, 64);
        if (lane >= off) incl += u;
    }
    int excl = incl - s;
    cnt[bin * NBLK_A + 2 * lane] = excl;
    cnt[bin * NBLK_A + 2 * lane + 1] = excl + c0;
    if (lane == 63) btot[bin] = incl;
}

// ---------------- exclusive scan of 196 bin totals -> bucket_start -----------
__global__ __launch_bounds__(64) void k_bstart(const int* __restrict__ btot,
                                               int* __restrict__ bstart) {
    const int lane = threadIdx.x;
    int v[4]; int s = 0;
#pragma unroll
    for (int j = 0; j < 4; ++j) {
        int i = 4 * lane + j;
        v[j] = (i < NBINS) ? btot[i] : 0;
        s += v[j];
    }
    int incl = s;
#pragma unroll
    for (int off = 1; off < 64; off <<= 1) {
        int u = __shfl_up(incl, off, 64);
        if (lane >= off) incl += u;
    }
    int run = incl - s;
#pragma unroll
    for (int j = 0; j < 4; ++j) {
        int i = 4 * lane + j;
        if (i < NBINS) bstart[i] = run;
        run += v[j];
    }
    if (lane == 63) bstart[NBINS] = TE;
}

// ---------------- scatter into coarse buckets (plain stores; r10 lesson) -----
// payload u32 = (dst&255)<<16 | src   (src < 65536)
__global__ __launch_bounds__(256) void k_scatter_coarse(const int* __restrict__ ei,
                                                        const int* __restrict__ cnt,
                                                        const int* __restrict__ bstart,
                                                        unsigned* __restrict__ cbuf) {
    __shared__ int cur[NBINS];
    const int t = threadIdx.x, blk = blockIdx.x;
    for (int i = t; i < NBINS; i += 256) cur[i] = cnt[i * NBLK_A + blk] + bstart[i];
    __syncthreads();
    const int e0 = blk * EPB, e1 = min(TE, e0 + EPB);
    for (int e = e0 + t; e < e1; e += 256) {
        int s, d;
        if (e < E_RAW) { s = ei[e]; d = ei[E_RAW + e]; }
        else { s = e - E_RAW; d = s; }
        int pos = atomicAdd(&cur[d >> 8], 1);   // LDS atomic
        cbuf[pos] = ((unsigned)(d & 255) << 16) | (unsigned)s;
    }
}

// ---------------- fine histogram -> deg --------------------
__global__ __launch_bounds__(256) void k_fine_hist(const unsigned* __restrict__ cbuf,
                                                   const int* __restrict__ bstart,
                                                   int* __restrict__ deg) {
    __shared__ int hist[256];
    const int t = threadIdx.x, b = blockIdx.x;
    hist[t] = 0;
    __syncthreads();
    const int i0 = bstart[b], i1 = bstart[b + 1];
    for (int i = i0 + t; i < i1; i += 256) atomicAdd(&hist[cbuf[i] >> 16], 1);
    __syncthreads();
    const int d = b * 256 + t;
    if (d < N_NODES) deg[d] = hist[t];
}

// ---------------- exclusive scan over 8-PADDED degrees (2-level) --------------
__global__ __launch_bounds__(1024) void k_scan1(const int* __restrict__ deg,
                                                int* __restrict__ incl, int* __restrict__ bsum) {
    int t = threadIdx.x, g = blockIdx.x;
    int idx = g * 1024 + t;
    int v = (idx < N_NODES) ? ((deg[idx] + 7) & ~7) : 0;
    int lane = t & 63, w = t >> 6;
#pragma unroll
    for (int off = 1; off < 64; off <<= 1) {
        int u = __shfl_up(v, off, 64);
        if (lane >= off) v += u;
    }
    __shared__ int ws[16];
    if (lane == 63) ws[w] = v;
    __syncthreads();
    if (w == 0 && lane < 16) {
        int s = ws[lane];
#pragma unroll
        for (int off = 1; off < 16; off <<= 1) {
            int u = __shfl_up(s, off, 16);
            if (lane >= off) s += u;
        }
        ws[lane] = s;
    }
    __syncthreads();
    if (w > 0) v += ws[w - 1];
    if (idx < N_NODES) incl[idx] = v;
    if (t == 1023) bsum[g] = v;
}

__global__ void k_scan2(int* __restrict__ bsum, int nblk) {
    int t = threadIdx.x;
    int v = (t < nblk) ? bsum[t] : 0;
#pragma unroll
    for (int off = 1; off < 64; off <<= 1) {
        int u = __shfl_up(v, off, 64);
        if (t >= off) v += u;
    }
    if (t < nblk) bsum[t] = v;
}

__global__ __launch_bounds__(1024) void k_scan3(const int* __restrict__ incl,
                                                const int* __restrict__ bsum,
                                                int* __restrict__ rowstart) {
    int idx = blockIdx.x * 1024 + threadIdx.x;
    if (idx >= N_NODES) return;
    int off = (blockIdx.x > 0) ? bsum[blockIdx.x - 1] : 0;
    rowstart[idx + 1] = incl[idx] + off;
    if (idx == 0) rowstart[0] = 0;
}

// ---------------- per-bucket scatter into csr (plain stores) -----------------
__global__ __launch_bounds__(256) void k_build_csr(const unsigned* __restrict__ cbuf,
                                                   const int* __restrict__ bstart,
                                                   const int* __restrict__ rowstart,
                                                   int* __restrict__ csr) {
    __shared__ int cur[256];
    const int t = threadIdx.x, b = blockIdx.x;
    const int d = b * 256 + t;
    cur[t] = (d < N_NODES) ? rowstart[d] : 0;
    __syncthreads();
    const int i0 = bstart[b], i1 = bstart[b + 1];
    for (int i = i0 + t; i < i1; i += 256) {
        unsigned v = cbuf[i];
        int pos = atomicAdd(&cur[v >> 16], 1);   // LDS atomic
        csr[pos] = (int)(v & 0xffffu);
    }
}

// ---------------- layer1 edge weights (bf16 planes) + pad zero-fill ----------
__global__ __launch_bounds__(256) void k_ew1(
    const int* __restrict__ rowstart, int* __restrict__ csr, const int* __restrict__ deg,
    const float* __restrict__ a1s, const float* __restrict__ a1d,
    unsigned short* __restrict__ ew1) {
    const int lane = threadIdx.x & 63;
    const int wid = threadIdx.x >> 6;
    const int n = blockIdx.x * 4 + wid;
    if (n >= N_NODES) return;
    const int rs = rowstart[n];
    const int dg = deg[n];
    const int re = rs + dg;
    const int re8 = rs + ((dg + 7) & ~7);
    const float4 ad = ((const float4*)a1d)[n];
    for (int i = rs + lane; i < re8; i += 64) {
        if (i < re) {
            int s = csr[i];
            float4 as = ((const float4*)a1s)[s];
            ew1[0 * TEP + i] = f2bf(expf(lrelu(as.x + ad.x)));
            ew1[1 * TEP + i] = f2bf(expf(lrelu(as.y + ad.y)));
            ew1[2 * TEP + i] = f2bf(expf(lrelu(as.z + ad.z)));
            ew1[3 * TEP + i] = f2bf(expf(lrelu(as.w + ad.w)));
        } else {
            csr[i] = 0;
            ew1[0 * TEP + i] = 0;
            ew1[1 * TEP + i] = 0;
            ew1[2 * TEP + i] = 0;
            ew1[3 * TEP + i] = 0;
        }
    }
}

// ---------------- layer1 gather: fp8 rows + bf16 weights, 8 edges/iter -------
__global__ __launch_bounds__(256) void k_l1_gather(
    const int* __restrict__ rowstart, const int* __restrict__ csr,
    const int* __restrict__ deg, const unsigned short* __restrict__ ew1,
    const unsigned short* __restrict__ xw8, const float* __restrict__ b1,
    float* __restrict__ h1) {
    const int lane = threadIdx.x & 63;
    const int wid = threadIdx.x >> 6;
    const int n = blockIdx.x * 4 + wid;
    if (n >= N_NODES) return;
    const int rs = rowstart[n];
    const int nb8 = (deg[n] + 7) >> 3;
    const int h = lane >> 4;
    const int4* c4 = (const int4*)(csr + rs);
    const ushort4* w4 = (const ushort4*)(ew1 + h * TEP + rs);
    float den = 0.f, ax = 0.f, ay = 0.f;
    for (int b = 0; b < nb8; ++b) {
        int4 sA = c4[2 * b], sB = c4[2 * b + 1];
        ushort4 wA = w4[2 * b], wB = w4[2 * b + 1];
        int u0 = xw8[sA.x * 64 + lane], u1 = xw8[sA.y * 64 + lane];
        int u2 = xw8[sA.z * 64 + lane], u3 = xw8[sA.w * 64 + lane];
        int u4 = xw8[sB.x * 64 + lane], u5 = xw8[sB.y * 64 + lane];
        int u6 = xw8[sB.z * 64 + lane], u7 = xw8[sB.w * 64 + lane];
        vf2 v0 = fp8pair2f(u0), v1 = fp8pair2f(u1), v2 = fp8pair2f(u2), v3 = fp8pair2f(u3);
        vf2 v4 = fp8pair2f(u4), v5 = fp8pair2f(u5), v6 = fp8pair2f(u6), v7 = fp8pair2f(u7);
        float wa0 = bf2f(wA.x), wa1 = bf2f(wA.y), wa2 = bf2f(wA.z), wa3 = bf2f(wA.w);
        float wb0 = bf2f(wB.x), wb1 = bf2f(wB.y), wb2 = bf2f(wB.z), wb3 = bf2f(wB.w);
        den += ((wa0 + wa1) + (wa2 + wa3)) + ((wb0 + wb1) + (wb2 + wb3));
        ax = fmaf(wa0, v0.x, fmaf(wa1, v1.x, fmaf(wa2, v2.x, fmaf(wa3, v3.x, ax))));
        ay = fmaf(wa0, v0.y, fmaf(wa1, v1.y, fmaf(wa2, v2.y, fmaf(wa3, v3.y, ay))));
        ax = fmaf(wb0, v4.x, fmaf(wb1, v5.x, fmaf(wb2, v6.x, fmaf(wb3, v7.x, ax))));
        ay = fmaf(wb0, v4.y, fmaf(wb1, v5.y, fmaf(wb2, v6.y, fmaf(wb3, v7.y, ay))));
    }
    const float inv = 1.f / (den + EPS_F);
    const int c0 = 2 * lane;
    float o0 = fmaf(ax, inv, b1[c0]);
    float o1 = fmaf(ay, inv, b1[c0 + 1]);
    o0 = o0 > 0.f ? o0 : expm1f(o0);
    o1 = o1 > 0.f ? o1 : expm1f(o1);
    ((float2*)h1)[(size_t)n * 64 + lane] = make_float2(o0, o1);
}

// ---------------- layer2 matmul via MFMA (fp8 out, single head) --------------
// 16 nodes/block, 4 waves; wave w computes channels [16w,16w+16) as one
// 16x16 C-tile over K=128. Cross-wave attention reduce via small LDS array.
__global__ __launch_bounds__(256) void k_l2_mm(
    const float* __restrict__ h1, const unsigned short* __restrict__ w2t,
    const float* __restrict__ atts, const float* __restrict__ attd,
    unsigned char* __restrict__ xwf8, float* __restrict__ a2s, float* __restrict__ a2d) {
    __shared__ __align__(16) unsigned short wls[F2 * XPAD];   // 17408 B
    __shared__ __align__(16) unsigned short xs[16 * XPAD];    // 4352 B
    __shared__ float parts[16][4], partd[16][4];
    const int t = threadIdx.x;
    const int n0 = blockIdx.x * 16;
    {
        const float4* src = (const float4*)(h1 + (size_t)n0 * F1);
#pragma unroll
        for (int i = 0; i < 2; ++i) {
            int idx = t + 256 * i;
            float4 v = src[idx];
            int row = idx >> 5;
            int col = (idx & 31) * 4;
            ushort4 o = { f2bf(v.x), f2bf(v.y), f2bf(v.z), f2bf(v.w) };
            *(ushort4*)(xs + row * XPAD + col) = o;
        }
        const uint4* wsrc = (const uint4*)w2t;  // 1024 uint4
#pragma unroll
        for (int i = 0; i < 4; ++i) {
            int idx = t + 256 * i;
            uint4 v = wsrc[idx];
            int row = idx >> 4;
            int col = (idx & 15) * 8;
            *(uint4*)(wls + row * XPAD + col) = v;
        }
    }
    __syncthreads();
    const int w = t >> 6;
    const int lane = t & 63;
    const int quad = lane >> 4;
    const int ncol = lane & 15;
    const int ch0 = w * 16;
    const unsigned short* arow = xs + ncol * XPAD;
    const unsigned short* brow = wls + (ch0 + ncol) * XPAD;
    f32x4 acc = {0.f, 0.f, 0.f, 0.f};
#pragma unroll
    for (int s = 0; s < 4; ++s) {
        int kb = s * 32 + quad * 8;
        short8 a = *(const short8*)(arow + kb);
        short8 b = *(const short8*)(brow + kb);
        acc = __builtin_amdgcn_mfma_f32_16x16x32_bf16(a, b, acc, 0, 0, 0);
    }
    const int ch = ch0 + ncol;
    const float asv = atts[ch], adv = attd[ch];
#pragma unroll
    for (int reg = 0; reg < 4; ++reg) {
        const int m = quad * 4 + reg;
        float v = acc[reg];
        xwf8[(size_t)(n0 + m) * F2 + ch] = f2fp8(v);
        float ps = v * asv, pd = v * adv;
#pragma unroll
        for (int off = 1; off < 16; off <<= 1) {
            ps += __shfl_xor(ps, off);
            pd += __shfl_xor(pd, off);
        }
        if (ncol == 0) { parts[m][w] = ps; partd[m][w] = pd; }
    }
    __syncthreads();
    if (t < 16) {
        a2s[n0 + t] = (parts[t][0] + parts[t][1]) + (parts[t][2] + parts[t][3]);
        a2d[n0 + t] = (partd[t][0] + partd[t][1]) + (partd[t][2] + partd[t][3]);
    }
}

// ---------------- layer2 edge weights (bf16) ----------------
__global__ __launch_bounds__(256) void k_ew2(
    const int* __restrict__ rowstart, const int* __restrict__ csr,
    const int* __restrict__ deg,
    const float* __restrict__ a2s, const float* __restrict__ a2d,
    unsigned short* __restrict__ ew2) {
    const int lane = threadIdx.x & 63;
    const int wid = threadIdx.x >> 6;
    const int n = blockIdx.x * 4 + wid;
    if (n >= N_NODES) return;
    const int rs = rowstart[n];
    const int dg = deg[n];
    const int re = rs + dg;
    const int re8 = rs + ((dg + 7) & ~7);
    const float adv = a2d[n];
    for (int i = rs + lane; i < re8; i += 64) {
        if (i < re) {
            int s = csr[i];
            ew2[i] = f2bf(expf(lrelu(a2s[s] + adv)));
        } else {
            ew2[i] = 0;
        }
    }
}

// ---------------- layer2 gather: fp8 rows + bf16 weights ---------------------
__global__ __launch_bounds__(256) void k_l2_gather(
    const int* __restrict__ rowstart, const int* __restrict__ csr,
    const int* __restrict__ deg, const unsigned short* __restrict__ ew2,
    const unsigned char* __restrict__ xw8, float* __restrict__ h2) {
    const int lane = threadIdx.x & 63;
    const int wid = threadIdx.x >> 6;
    const int n = blockIdx.x * 4 + wid;
    if (n >= N_NODES) return;
    const int rs = rowstart[n];
    const int nb8 = (deg[n] + 7) >> 3;
    const int4* c4 = (const int4*)(csr + rs);
    const ushort4* w4 = (const ushort4*)(ew2 + rs);
    float den = 0.f, acc = 0.f;
    for (int b = 0; b < nb8; ++b) {
        int4 sA = c4[2 * b], sB = c4[2 * b + 1];
        ushort4 wA = w4[2 * b], wB = w4[2 * b + 1];
        int u0 = xw8[(size_t)sA.x * F2 + lane], u1 = xw8[(size_t)sA.y * F2 + lane];
        int u2 = xw8[(size_t)sA.z * F2 + lane], u3 = xw8[(size_t)sA.w * F2 + lane];
        int u4 = xw8[(size_t)sB.x * F2 + lane], u5 = xw8[(size_t)sB.y * F2 + lane];
        int u6 = xw8[(size_t)sB.z * F2 + lane], u7 = xw8[(size_t)sB.w * F2 + lane];
        float v0 = fp8pair2f(u0).x, v1 = fp8pair2f(u1).x;
        float v2 = fp8pair2f(u2).x, v3 = fp8pair2f(u3).x;
        float v4 = fp8pair2f(u4).x, v5 = fp8pair2f(u5).x;
        float v6 = fp8pair2f(u6).x, v7 = fp8pair2f(u7).x;
        float wa0 = bf2f(wA.x), wa1 = bf2f(wA.y), wa2 = bf2f(wA.z), wa3 = bf2f(wA.w);
        float wb0 = bf2f(wB.x), wb1 = bf2f(wB.y), wb2 = bf2f(wB.z), wb3 = bf2f(wB.w);
        den += ((wa0 + wa1) + (wa2 + wa3)) + ((wb0 + wb1) + (wb2 + wb3));
        acc = fmaf(wa0, v0, fmaf(wa1, v1, fmaf(wa2, v2, fmaf(wa3, v3, acc))));
        acc = fmaf(wb0, v4, fmaf(wb1, v5, fmaf(wb2, v6, fmaf(wb3, v7, acc))));
    }
    h2[(size_t)n * F2 + lane] = acc / (den + EPS_F);
}

// ---------------- mean over nodes (fp64 accum) ----------------
#define MEAN_BLOCKS 256
__global__ __launch_bounds__(256) void k_mean(const float* __restrict__ h2,
                                              double* __restrict__ accum) {
    const int t = threadIdx.x;
    const int c = t & 63;
    double acc = 0.0;
    const size_t total = (size_t)N_NODES * F2;
    for (size_t idx = (size_t)blockIdx.x * 256 + t; idx < total; idx += (size_t)MEAN_BLOCKS * 256)
        acc += (double)h2[idx];
    __shared__ double red[256];
    red[t] = acc;
    __syncthreads();
    if (t < 64) {
        double v = red[t] + red[t + 64] + red[t + 128] + red[t + 192];
        atomicAdd(&accum[c], v);
    }
}

__global__ void k_final(const double* __restrict__ accum, const float* __restrict__ b2,
                        float* __restrict__ out) {
    int t = threadIdx.x;
    if (t < F2) out[t] = (float)(accum[t] * (1.0 / (double)N_NODES)) + b2[t];
}

// ---------------- launch ----------------
extern "C" void kernel_launch(void* const* d_in, const int* in_sizes, int n_in,
                              void* d_out, int out_size, void* d_ws, size_t ws_size,
                              hipStream_t stream) {
    (void)in_sizes; (void)n_in; (void)out_size; (void)ws_size;
    const float* x   = (const float*)d_in[0];
    const int*   ei  = (const int*)d_in[1];
    const float* W1  = (const float*)d_in[2];
    const float* as1 = (const float*)d_in[3];
    const float* ad1 = (const float*)d_in[4];
    const float* b1  = (const float*)d_in[5];
    const float* W2  = (const float*)d_in[6];
    const float* as2 = (const float*)d_in[7];
    const float* ad2 = (const float*)d_in[8];
    const float* b2  = (const float*)d_in[9];
    float* out = (float*)d_out;

    char* ws = (char*)d_ws;
    size_t off = 0;
    auto alloc = [&](size_t bytes) -> void* {
        void* p = ws + off;
        off += (bytes + 255) & ~(size_t)255;
        return p;
    };
    unsigned char*  xw1f8 = (unsigned char*)alloc((size_t)N_NODES * F1);
    float* h1       = (float*)alloc((size_t)N_NODES * F1 * 4);
    unsigned char*  xw2f8 = (unsigned char*)alloc((size_t)N_NODES * F2);
    float* h2       = (float*)alloc((size_t)N_NODES * F2 * 4);
    unsigned short* ew1 = (unsigned short*)alloc((size_t)H1 * TEP * 2);
    unsigned short* ew2 = (unsigned short*)alloc((size_t)TEP * 2);
    unsigned short* w1t = (unsigned short*)alloc((size_t)F1 * F1 * 2);
    unsigned short* w2t = (unsigned short*)alloc((size_t)F2 * F1 * 2);
    float* a1s      = (float*)alloc((size_t)N_NODES * H1 * 4);
    float* a1d      = (float*)alloc((size_t)N_NODES * H1 * 4);
    float* a2s      = (float*)alloc((size_t)N_NODES * 4);
    float* a2d      = (float*)alloc((size_t)N_NODES * 4);
    int*   deg      = (int*)alloc((size_t)N_NODES * 4);
    unsigned* cbuf  = (unsigned*)alloc((size_t)TE * 4);
    int*   cnt      = (int*)alloc((size_t)NBINS * NBLK_A * 4);
    int*   btot     = (int*)alloc((size_t)NBINS * 4);
    int*   bstart   = (int*)alloc((size_t)(NBINS + 1) * 4);
    int*   rowstart = (int*)alloc((size_t)(N_NODES + 1) * 4);
    int*   csr      = (int*)alloc((size_t)TEP * 4);
    int*   incl     = (int*)alloc((size_t)N_NODES * 4);
    int*   bsum     = (int*)alloc(64 * 4);
    double* accum   = (double*)alloc(F2 * 8);

    const int nscan = (N_NODES + 1023) / 1024;  // 49
    const int nwave4 = (N_NODES + 3) / 4;       // 12500

    hipMemsetAsync(accum, 0, F2 * 8, stream);
    k_prep<<<96, 256, 0, stream>>>(W1, W2, w1t, w2t);
    k_l1_mm_hist<<<MM_BLOCKS + NBLK_A, 256, 0, stream>>>(x, w1t, as1, ad1, xw1f8, a1s, a1d, ei, cnt);
    k_btot<<<NBINS, 64, 0, stream>>>(cnt, btot);
    k_bstart<<<1, 64, 0, stream>>>(btot, bstart);
    k_scatter_coarse<<<NBLK_A, 256, 0, stream>>>(ei, cnt, bstart, cbuf);
    k_fine_hist<<<NBINS, 256, 0, stream>>>(cbuf, bstart, deg);
    k_scan1<<<nscan, 1024, 0, stream>>>(deg, incl, bsum);
    k_scan2<<<1, 64, 0, stream>>>(bsum, nscan);
    k_scan3<<<nscan, 1024, 0, stream>>>(incl, bsum, rowstart);
    k_build_csr<<<NBINS, 256, 0, stream>>>(cbuf, bstart, rowstart, csr);
    k_ew1<<<nwave4, 256, 0, stream>>>(rowstart, csr, deg, a1s, a1d, ew1);
    k_l1_gather<<<nwave4, 256, 0, stream>>>(rowstart, csr, deg, ew1,
                                            (const unsigned short*)xw1f8, b1, h1);
    k_l2_mm<<<MM_BLOCKS, 256, 0, stream>>>(h1, w2t, as2, ad2, xw2f8, a2s, a2d);
    k_ew2<<<nwave4, 256, 0, stream>>>(rowstart, csr, deg, a2s, a2d, ew2);
    k_l2_gather<<<nwave4, 256, 0, stream>>>(rowstart, csr, deg, ew2, xw2f8, h2);
    k_mean<<<MEAN_BLOCKS, 256, 0, stream>>>(h2, accum);
    k_final<<<1, 64, 0, stream>>>(accum, b2, out);
}

// Round 14
// 274.213 us; speedup vs baseline: 1.3346x; 1.1453x over previous
//
#include <hip/hip_runtime.h>
#include <math.h>

#define N_NODES 50000
#define SN      N_NODES               // sentinel node id for CSR pads
#define E_RAW   1600000
#define TE      (E_RAW + N_NODES)     // 1650000 edges incl. self loops
#define TEP     (TE + 16 * N_NODES)   // CSR padded to 16-aligned rows (upper bound)
#define F_IN    128
#define H1      4
#define F1      128                   // H1*C1
#define F2      64
#define NEG_SLOPE 0.2f
#define EPS_F   1e-16f
#define XPAD    136                   // LDS row stride in bf16 (kills bank conflicts)

// ---- bucket-sort CSR build params (all atomics are LDS-scope) ----
#define NBINS   196                   // coarse buckets: dst >> 8
#define NBLK_A  128                   // blocks in coarse hist/scatter
#define EPB     ((TE + NBLK_A - 1) / NBLK_A)
#define MM_BLOCKS (N_NODES / 16)      // 3125

__device__ __forceinline__ float lrelu(float v) { return v > 0.f ? v : NEG_SLOPE * v; }

typedef float vf2 __attribute__((ext_vector_type(2)));
typedef short short8 __attribute__((ext_vector_type(8)));
typedef float f32x4 __attribute__((ext_vector_type(4)));

__device__ __forceinline__ unsigned short f2bf(float f) {
    unsigned u = __float_as_uint(f);
    return (unsigned short)((u + 0x7fffu + ((u >> 16) & 1u)) >> 16);
}
__device__ __forceinline__ unsigned char f2fp8(float f) {
    int p = __builtin_amdgcn_cvt_pk_fp8_f32(f, f, 0, false);
    return (unsigned char)(p & 0xff);
}
__device__ __forceinline__ vf2 fp8lo(unsigned u) {   // bytes 0,1 -> 2 floats
    return __builtin_amdgcn_cvt_pk_f32_fp8((int)u, false);
}
__device__ __forceinline__ vf2 fp8hi(unsigned u) {   // bytes 2,3 -> 2 floats
    return __builtin_amdgcn_cvt_pk_f32_fp8((int)u, true);
}

// ---------------- prep: W -> transposed bf16 [c][k]; sentinel logits ---------
__global__ __launch_bounds__(256) void k_prep(const float* __restrict__ W1,
                                              const float* __restrict__ W2,
                                              unsigned short* __restrict__ w1t,
                                              unsigned short* __restrict__ w2t,
                                              float* __restrict__ a1s,
                                              float* __restrict__ a2s) {
    int idx = blockIdx.x * 256 + threadIdx.x;   // 96 blocks: 16384 + 8192
    if (idx < 16384) {
        int c = idx >> 7, k = idx & 127;
        w1t[idx] = f2bf(W1[k * F1 + c]);
    } else {
        int j = idx - 16384;
        int c = j >> 7, k = j & 127;
        w2t[j] = f2bf(W2[k * F2 + c]);
    }
    if (blockIdx.x == 0 && threadIdx.x < H1) a1s[SN * H1 + threadIdx.x] = -1e30f;
    if (blockIdx.x == 0 && threadIdx.x == H1) a2s[SN] = -1e30f;
}

// ---------------- layer1 matmul via MFMA (+ fused coarse histogram) ----------
__global__ __launch_bounds__(256) void k_l1_mm_hist(
    const float* __restrict__ x, const unsigned short* __restrict__ w1t,
    const float* __restrict__ atts, const float* __restrict__ attd,
    unsigned char* __restrict__ xwf8, float* __restrict__ a1s, float* __restrict__ a1d,
    const int* __restrict__ ei, int* __restrict__ cnt) {
    __shared__ __align__(16) unsigned short wls[F1 * XPAD];
    __shared__ __align__(16) unsigned short xs[16 * XPAD];
    const int t = threadIdx.x;
    if (blockIdx.x >= MM_BLOCKS) {
        int* hist = (int*)wls;
        const int blk = blockIdx.x - MM_BLOCKS;
        for (int i = t; i < NBINS; i += 256) hist[i] = 0;
        __syncthreads();
        const int e0 = blk * EPB, e1 = min(TE, e0 + EPB);
        for (int e = e0 + t; e < e1; e += 256) {
            int d = (e < E_RAW) ? ei[E_RAW + e] : (e - E_RAW);
            atomicAdd(&hist[d >> 8], 1);
        }
        __syncthreads();
        for (int i = t; i < NBINS; i += 256) cnt[i * NBLK_A + blk] = hist[i];
        return;
    }
    const int n0 = blockIdx.x * 16;
    {
        const float4* src = (const float4*)(x + (size_t)n0 * F_IN);
#pragma unroll
        for (int i = 0; i < 2; ++i) {
            int idx = t + 256 * i;
            float4 v = src[idx];
            int row = idx >> 5;
            int col = (idx & 31) * 4;
            ushort4 o = { f2bf(v.x), f2bf(v.y), f2bf(v.z), f2bf(v.w) };
            *(ushort4*)(xs + row * XPAD + col) = o;
        }
        const uint4* wsrc = (const uint4*)w1t;
#pragma unroll
        for (int i = 0; i < 8; ++i) {
            int idx = t + 256 * i;
            uint4 v = wsrc[idx];
            int row = idx >> 4;
            int col = (idx & 15) * 8;
            *(uint4*)(wls + row * XPAD + col) = v;
        }
    }
    __syncthreads();
    const int w = t >> 6;         // wave = head
    const int lane = t & 63;
    const int quad = lane >> 4;
    const int ncol = lane & 15;
    const int ch0 = w * 32;
    const unsigned short* arow = xs + ncol * XPAD;
    const unsigned short* brow0 = wls + (ch0 + ncol) * XPAD;
    const unsigned short* brow1 = brow0 + 16 * XPAD;
    f32x4 acc0 = {0.f, 0.f, 0.f, 0.f}, acc1 = {0.f, 0.f, 0.f, 0.f};
#pragma unroll
    for (int s = 0; s < 4; ++s) {
        int kb = s * 32 + quad * 8;
        short8 a  = *(const short8*)(arow + kb);
        short8 b0 = *(const short8*)(brow0 + kb);
        short8 b1 = *(const short8*)(brow1 + kb);
        acc0 = __builtin_amdgcn_mfma_f32_16x16x32_bf16(a, b0, acc0, 0, 0, 0);
        acc1 = __builtin_amdgcn_mfma_f32_16x16x32_bf16(a, b1, acc1, 0, 0, 0);
    }
    const int ch = ch0 + ncol;
    const float as0 = atts[ch], as1 = atts[ch + 16];
    const float ad0 = attd[ch], ad1 = attd[ch + 16];
#pragma unroll
    for (int reg = 0; reg < 4; ++reg) {
        const int n = n0 + quad * 4 + reg;
        float v0 = acc0[reg], v1 = acc1[reg];
        xwf8[(size_t)n * F1 + ch] = f2fp8(v0);
        xwf8[(size_t)n * F1 + ch + 16] = f2fp8(v1);
        float ps = fmaf(v0, as0, v1 * as1);
        float pd = fmaf(v0, ad0, v1 * ad1);
#pragma unroll
        for (int off = 1; off < 16; off <<= 1) {
            ps += __shfl_xor(ps, off);
            pd += __shfl_xor(pd, off);
        }
        if (ncol == 0) {
            a1s[n * H1 + w] = ps;
            a1d[n * H1 + w] = pd;
        }
    }
}

// ---------------- per-bin scan of cnt across blocks + bin totals -------------
__global__ __launch_bounds__(64) void k_btot(int* __restrict__ cnt, int* __restrict__ btot) {
    const int bin = blockIdx.x, lane = threadIdx.x;
    int c0 = cnt[bin * NBLK_A + 2 * lane];
    int c1 = cnt[bin * NBLK_A + 2 * lane + 1];
    int s = c0 + c1;
    int incl = s;
#pragma unroll
    for (int off = 1; off < 64; off <<= 1) {
        int u = __shfl_up(incl, off, 64);
        if (lane >= off) incl += u;
    }
    int excl = incl - s;
    cnt[bin * NBLK_A + 2 * lane] = excl;
    cnt[bin * NBLK_A + 2 * lane + 1] = excl + c0;
    if (lane == 63) btot[bin] = incl;
}

// ---------------- exclusive scan of 196 bin totals -> bucket_start -----------
__global__ __launch_bounds__(64) void k_bstart(const int* __restrict__ btot,
                                               int* __restrict__ bstart) {
    const int lane = threadIdx.x;
    int v[4]; int s = 0;
#pragma unroll
    for (int j = 0; j < 4; ++j) {
        int i = 4 * lane + j;
        v[j] = (i < NBINS) ? btot[i] : 0;
        s += v[j];
    }
    int incl = s;
#pragma unroll
    for (int off = 1; off < 64; off <<= 1) {
        int u = __shfl_up(incl, off, 64);
        if (lane >= off) incl += u;
    }
    int run = incl - s;
#pragma unroll
    for (int j = 0; j < 4; ++j) {
        int i = 4 * lane + j;
        if (i < NBINS) bstart[i] = run;
        run += v[j];
    }
    if (lane == 63) bstart[NBINS] = TE;
}

// ---------------- scatter into coarse buckets (plain stores) -----------------
__global__ __launch_bounds__(256) void k_scatter_coarse(const int* __restrict__ ei,
                                                        const int* __restrict__ cnt,
                                                        const int* __restrict__ bstart,
                                                        unsigned* __restrict__ cbuf) {
    __shared__ int cur[NBINS];
    const int t = threadIdx.x, blk = blockIdx.x;
    for (int i = t; i < NBINS; i += 256) cur[i] = cnt[i * NBLK_A + blk] + bstart[i];
    __syncthreads();
    const int e0 = blk * EPB, e1 = min(TE, e0 + EPB);
    for (int e = e0 + t; e < e1; e += 256) {
        int s, d;
        if (e < E_RAW) { s = ei[e]; d = ei[E_RAW + e]; }
        else { s = e - E_RAW; d = s; }
        int pos = atomicAdd(&cur[d >> 8], 1);   // LDS atomic
        cbuf[pos] = ((unsigned)(d & 255) << 16) | (unsigned)s;
    }
}

// ---------------- fine histogram -> deg --------------------
__global__ __launch_bounds__(256) void k_fine_hist(const unsigned* __restrict__ cbuf,
                                                   const int* __restrict__ bstart,
                                                   int* __restrict__ deg) {
    __shared__ int hist[256];
    const int t = threadIdx.x, b = blockIdx.x;
    hist[t] = 0;
    __syncthreads();
    const int i0 = bstart[b], i1 = bstart[b + 1];
    for (int i = i0 + t; i < i1; i += 256) atomicAdd(&hist[cbuf[i] >> 16], 1);
    __syncthreads();
    const int d = b * 256 + t;
    if (d < N_NODES) deg[d] = hist[t];
}

// ---------------- exclusive scan over 16-PADDED degrees (2-level) ------------
__global__ __launch_bounds__(1024) void k_scan1(const int* __restrict__ deg,
                                                int* __restrict__ incl, int* __restrict__ bsum) {
    int t = threadIdx.x, g = blockIdx.x;
    int idx = g * 1024 + t;
    int v = (idx < N_NODES) ? ((deg[idx] + 15) & ~15) : 0;
    int lane = t & 63, w = t >> 6;
#pragma unroll
    for (int off = 1; off < 64; off <<= 1) {
        int u = __shfl_up(v, off, 64);
        if (lane >= off) v += u;
    }
    __shared__ int ws[16];
    if (lane == 63) ws[w] = v;
    __syncthreads();
    if (w == 0 && lane < 16) {
        int s = ws[lane];
#pragma unroll
        for (int off = 1; off < 16; off <<= 1) {
            int u = __shfl_up(s, off, 16);
            if (lane >= off) s += u;
        }
        ws[lane] = s;
    }
    __syncthreads();
    if (w > 0) v += ws[w - 1];
    if (idx < N_NODES) incl[idx] = v;
    if (t == 1023) bsum[g] = v;
}

__global__ void k_scan2(int* __restrict__ bsum, int nblk) {
    int t = threadIdx.x;
    int v = (t < nblk) ? bsum[t] : 0;
#pragma unroll
    for (int off = 1; off < 64; off <<= 1) {
        int u = __shfl_up(v, off, 64);
        if (t >= off) v += u;
    }
    if (t < nblk) bsum[t] = v;
}

__global__ __launch_bounds__(1024) void k_scan3(const int* __restrict__ incl,
                                                const int* __restrict__ bsum,
                                                int* __restrict__ rowstart) {
    int idx = blockIdx.x * 1024 + threadIdx.x;
    if (idx >= N_NODES) return;
    int off = (blockIdx.x > 0) ? bsum[blockIdx.x - 1] : 0;
    rowstart[idx + 1] = incl[idx] + off;
    if (idx == 0) rowstart[0] = 0;
}

// ---------------- per-bucket scatter into csr + sentinel pad fill ------------
// cur[t] ends at rowstart[d]+deg[d]; pads get src=SN whose logit is -1e30 ->
// weight exp(lrelu(-inf)) = 0 exactly, so pad edges contribute nothing.
__global__ __launch_bounds__(256) void k_build_csr(const unsigned* __restrict__ cbuf,
                                                   const int* __restrict__ bstart,
                                                   const int* __restrict__ rowstart,
                                                   const int* __restrict__ deg,
                                                   int* __restrict__ csr) {
    __shared__ int cur[256];
    const int t = threadIdx.x, b = blockIdx.x;
    const int d = b * 256 + t;
    cur[t] = (d < N_NODES) ? rowstart[d] : 0;
    __syncthreads();
    const int i0 = bstart[b], i1 = bstart[b + 1];
    for (int i = i0 + t; i < i1; i += 256) {
        unsigned v = cbuf[i];
        int pos = atomicAdd(&cur[v >> 16], 1);   // LDS atomic
        csr[pos] = (int)(v & 0xffffu);
    }
    __syncthreads();
    if (d < N_NODES) {
        const int pend = rowstart[d] + ((deg[d] + 15) & ~15);
        for (int i = cur[t]; i < pend; ++i) csr[i] = SN;
    }
}

// ---------------- layer1 gather: fused weights, 4ch/lane, 16 edges/iter ------
// Half-waves process 8 edges each: 8 value gathers (uint = 4 fp8 ch) + 8 logit
// gathers (dword, broadcast within each 8-lane head-octet) per 16 edges.
// Weight = __expf(lrelu(a1s[src][h]+a1d[n][h])) computed inline (ew kernels
// deleted). Cross-half combine via shfl_xor(32); half 0 writes float4.
__global__ __launch_bounds__(256) void k_l1_gather(
    const int* __restrict__ rowstart, const int* __restrict__ csr,
    const int* __restrict__ deg, const float* __restrict__ a1s,
    const float* __restrict__ a1d, const unsigned* __restrict__ xwu,
    const float* __restrict__ b1, float* __restrict__ h1) {
    const int lane = threadIdx.x & 63;
    const int wid = threadIdx.x >> 6;
    const int n = blockIdx.x * 4 + wid;
    if (n >= N_NODES) return;
    const int rs = rowstart[n];
    const int nb16 = (deg[n] + 15) >> 4;
    const int half = lane >> 5;
    const int sub = lane & 31;          // channel group 4*sub..4*sub+3
    const int h = sub >> 3;             // head
    const float adh = a1d[n * H1 + h];
    const int4* c4 = (const int4*)(csr + rs);
    float den = 0.f, f0 = 0.f, f1 = 0.f, f2 = 0.f, f3 = 0.f;
    for (int b = 0; b < nb16; ++b) {
        const int i0 = 4 * b + 2 * half;
        int4 sA = c4[i0], sB = c4[i0 + 1];
        float as0 = a1s[sA.x * H1 + h], as1 = a1s[sA.y * H1 + h];
        float as2 = a1s[sA.z * H1 + h], as3 = a1s[sA.w * H1 + h];
        float as4 = a1s[sB.x * H1 + h], as5 = a1s[sB.y * H1 + h];
        float as6 = a1s[sB.z * H1 + h], as7 = a1s[sB.w * H1 + h];
        unsigned u0 = xwu[sA.x * 32 + sub], u1 = xwu[sA.y * 32 + sub];
        unsigned u2 = xwu[sA.z * 32 + sub], u3 = xwu[sA.w * 32 + sub];
        unsigned u4 = xwu[sB.x * 32 + sub], u5 = xwu[sB.y * 32 + sub];
        unsigned u6 = xwu[sB.z * 32 + sub], u7 = xwu[sB.w * 32 + sub];
        float w0 = __expf(lrelu(as0 + adh));
        float w1 = __expf(lrelu(as1 + adh));
        float w2 = __expf(lrelu(as2 + adh));
        float w3 = __expf(lrelu(as3 + adh));
        float w4 = __expf(lrelu(as4 + adh));
        float w5 = __expf(lrelu(as5 + adh));
        float w6 = __expf(lrelu(as6 + adh));
        float w7 = __expf(lrelu(as7 + adh));
        den += ((w0 + w1) + (w2 + w3)) + ((w4 + w5) + (w6 + w7));
        vf2 l0 = fp8lo(u0), v0 = fp8hi(u0);
        f0 = fmaf(w0, l0.x, f0); f1 = fmaf(w0, l0.y, f1);
        f2 = fmaf(w0, v0.x, f2); f3 = fmaf(w0, v0.y, f3);
        vf2 l1 = fp8lo(u1), v1 = fp8hi(u1);
        f0 = fmaf(w1, l1.x, f0); f1 = fmaf(w1, l1.y, f1);
        f2 = fmaf(w1, v1.x, f2); f3 = fmaf(w1, v1.y, f3);
        vf2 l2 = fp8lo(u2), v2 = fp8hi(u2);
        f0 = fmaf(w2, l2.x, f0); f1 = fmaf(w2, l2.y, f1);
        f2 = fmaf(w2, v2.x, f2); f3 = fmaf(w2, v2.y, f3);
        vf2 l3 = fp8lo(u3), v3 = fp8hi(u3);
        f0 = fmaf(w3, l3.x, f0); f1 = fmaf(w3, l3.y, f1);
        f2 = fmaf(w3, v3.x, f2); f3 = fmaf(w3, v3.y, f3);
        vf2 l4 = fp8lo(u4), v4 = fp8hi(u4);
        f0 = fmaf(w4, l4.x, f0); f1 = fmaf(w4, l4.y, f1);
        f2 = fmaf(w4, v4.x, f2); f3 = fmaf(w4, v4.y, f3);
        vf2 l5 = fp8lo(u5), v5 = fp8hi(u5);
        f0 = fmaf(w5, l5.x, f0); f1 = fmaf(w5, l5.y, f1);
        f2 = fmaf(w5, v5.x, f2); f3 = fmaf(w5, v5.y, f3);
        vf2 l6 = fp8lo(u6), v6 = fp8hi(u6);
        f0 = fmaf(w6, l6.x, f0); f1 = fmaf(w6, l6.y, f1);
        f2 = fmaf(w6, v6.x, f2); f3 = fmaf(w6, v6.y, f3);
        vf2 l7 = fp8lo(u7), v7 = fp8hi(u7);
        f0 = fmaf(w7, l7.x, f0); f1 = fmaf(w7, l7.y, f1);
        f2 = fmaf(w7, v7.x, f2); f3 = fmaf(w7, v7.y, f3);
    }
    f0 += __shfl_xor(f0, 32);
    f1 += __shfl_xor(f1, 32);
    f2 += __shfl_xor(f2, 32);
    f3 += __shfl_xor(f3, 32);
    den += __shfl_xor(den, 32);
    if (half == 0) {
        const float inv = 1.f / (den + EPS_F);
        float4 bb = ((const float4*)b1)[sub];
        float o0 = fmaf(f0, inv, bb.x);
        float o1 = fmaf(f1, inv, bb.y);
        float o2 = fmaf(f2, inv, bb.z);
        float o3 = fmaf(f3, inv, bb.w);
        o0 = o0 > 0.f ? o0 : expm1f(o0);
        o1 = o1 > 0.f ? o1 : expm1f(o1);
        o2 = o2 > 0.f ? o2 : expm1f(o2);
        o3 = o3 > 0.f ? o3 : expm1f(o3);
        ((float4*)h1)[(size_t)n * 32 + sub] = make_float4(o0, o1, o2, o3);
    }
}

// ---------------- layer2 matmul via MFMA (fp8 out, single head) --------------
__global__ __launch_bounds__(256) void k_l2_mm(
    const float* __restrict__ h1, const unsigned short* __restrict__ w2t,
    const float* __restrict__ atts, const float* __restrict__ attd,
    unsigned char* __restrict__ xwf8, float* __restrict__ a2s, float* __restrict__ a2d) {
    __shared__ __align__(16) unsigned short wls[F2 * XPAD];
    __shared__ __align__(16) unsigned short xs[16 * XPAD];
    __shared__ float parts[16][4], partd[16][4];
    const int t = threadIdx.x;
    const int n0 = blockIdx.x * 16;
    {
        const float4* src = (const float4*)(h1 + (size_t)n0 * F1);
#pragma unroll
        for (int i = 0; i < 2; ++i) {
            int idx = t + 256 * i;
            float4 v = src[idx];
            int row = idx >> 5;
            int col = (idx & 31) * 4;
            ushort4 o = { f2bf(v.x), f2bf(v.y), f2bf(v.z), f2bf(v.w) };
            *(ushort4*)(xs + row * XPAD + col) = o;
        }
        const uint4* wsrc = (const uint4*)w2t;
#pragma unroll
        for (int i = 0; i < 4; ++i) {
            int idx = t + 256 * i;
            uint4 v = wsrc[idx];
            int row = idx >> 4;
            int col = (idx & 15) * 8;
            *(uint4*)(wls + row * XPAD + col) = v;
        }
    }
    __syncthreads();
    const int w = t >> 6;
    const int lane = t & 63;
    const int quad = lane >> 4;
    const int ncol = lane & 15;
    const int ch0 = w * 16;
    const unsigned short* arow = xs + ncol * XPAD;
    const unsigned short* brow = wls + (ch0 + ncol) * XPAD;
    f32x4 acc = {0.f, 0.f, 0.f, 0.f};
#pragma unroll
    for (int s = 0; s < 4; ++s) {
        int kb = s * 32 + quad * 8;
        short8 a = *(const short8*)(arow + kb);
        short8 b = *(const short8*)(brow + kb);
        acc = __builtin_amdgcn_mfma_f32_16x16x32_bf16(a, b, acc, 0, 0, 0);
    }
    const int ch = ch0 + ncol;
    const float asv = atts[ch], adv = attd[ch];
#pragma unroll
    for (int reg = 0; reg < 4; ++reg) {
        const int m = quad * 4 + reg;
        float v = acc[reg];
        xwf8[(size_t)(n0 + m) * F2 + ch] = f2fp8(v);
        float ps = v * asv, pd = v * adv;
#pragma unroll
        for (int off = 1; off < 16; off <<= 1) {
            ps += __shfl_xor(ps, off);
            pd += __shfl_xor(pd, off);
        }
        if (ncol == 0) { parts[m][w] = ps; partd[m][w] = pd; }
    }
    __syncthreads();
    if (t < 16) {
        a2s[n0 + t] = (parts[t][0] + parts[t][1]) + (parts[t][2] + parts[t][3]);
        a2d[n0 + t] = (partd[t][0] + partd[t][1]) + (partd[t][2] + partd[t][3]);
    }
}

// ---------------- layer2 gather: fused weights, 4ch/lane, 16 edges/iter ------
// Quarter-waves: lane quarter q handles edges 16b+q+4j; 4 value gathers per
// 16 edges per lane. Final reduce shfl_xor(16,32); lanes<16 write float4.
__global__ __launch_bounds__(256) void k_l2_gather(
    const int* __restrict__ rowstart, const int* __restrict__ csr,
    const int* __restrict__ deg, const float* __restrict__ a2s,
    const float* __restrict__ a2d, const unsigned* __restrict__ xwu,
    float* __restrict__ h2) {
    const int lane = threadIdx.x & 63;
    const int wid = threadIdx.x >> 6;
    const int n = blockIdx.x * 4 + wid;
    if (n >= N_NODES) return;
    const int rs = rowstart[n];
    const int nb16 = (deg[n] + 15) >> 4;
    const int q = lane >> 4;
    const int sub = lane & 15;          // channel group 4*sub..4*sub+3
    const float adv = a2d[n];
    float den = 0.f, f0 = 0.f, f1 = 0.f, f2 = 0.f, f3 = 0.f;
    for (int b = 0; b < nb16; ++b) {
        const int e = rs + 16 * b + q;
        int s0 = csr[e], s1 = csr[e + 4], s2 = csr[e + 8], s3 = csr[e + 12];
        float as0 = a2s[s0], as1 = a2s[s1], as2 = a2s[s2], as3 = a2s[s3];
        unsigned u0 = xwu[s0 * 16 + sub], u1 = xwu[s1 * 16 + sub];
        unsigned u2 = xwu[s2 * 16 + sub], u3 = xwu[s3 * 16 + sub];
        float w0 = __expf(lrelu(as0 + adv));
        float w1 = __expf(lrelu(as1 + adv));
        float w2 = __expf(lrelu(as2 + adv));
        float w3 = __expf(lrelu(as3 + adv));
        den += (w0 + w1) + (w2 + w3);
        vf2 l0 = fp8lo(u0), v0 = fp8hi(u0);
        f0 = fmaf(w0, l0.x, f0); f1 = fmaf(w0, l0.y, f1);
        f2 = fmaf(w0, v0.x, f2); f3 = fmaf(w0, v0.y, f3);
        vf2 l1 = fp8lo(u1), v1 = fp8hi(u1);
        f0 = fmaf(w1, l1.x, f0); f1 = fmaf(w1, l1.y, f1);
        f2 = fmaf(w1, v1.x, f2); f3 = fmaf(w1, v1.y, f3);
        vf2 l2 = fp8lo(u2), v2 = fp8hi(u2);
        f0 = fmaf(w2, l2.x, f0); f1 = fmaf(w2, l2.y, f1);
        f2 = fmaf(w2, v2.x, f2); f3 = fmaf(w2, v2.y, f3);
        vf2 l3 = fp8lo(u3), v3 = fp8hi(u3);
        f0 = fmaf(w3, l3.x, f0); f1 = fmaf(w3, l3.y, f1);
        f2 = fmaf(w3, v3.x, f2); f3 = fmaf(w3, v3.y, f3);
    }
#pragma unroll
    for (int off = 16; off <= 32; off <<= 1) {
        f0 += __shfl_xor(f0, off);
        f1 += __shfl_xor(f1, off);
        f2 += __shfl_xor(f2, off);
        f3 += __shfl_xor(f3, off);
        den += __shfl_xor(den, off);
    }
    if (lane < 16) {
        const float inv = 1.f / (den + EPS_F);
        ((float4*)h2)[(size_t)n * 16 + sub] =
            make_float4(f0 * inv, f1 * inv, f2 * inv, f3 * inv);
    }
}

// ---------------- mean over nodes (fp64 accum) ----------------
#define MEAN_BLOCKS 256
__global__ __launch_bounds__(256) void k_mean(const float* __restrict__ h2,
                                              double* __restrict__ accum) {
    const int t = threadIdx.x;
    const int c = t & 63;
    double acc = 0.0;
    const size_t total = (size_t)N_NODES * F2;
    for (size_t idx = (size_t)blockIdx.x * 256 + t; idx < total; idx += (size_t)MEAN_BLOCKS * 256)
        acc += (double)h2[idx];
    __shared__ double red[256];
    red[t] = acc;
    __syncthreads();
    if (t < 64) {
        double v = red[t] + red[t + 64] + red[t + 128] + red[t + 192];
        atomicAdd(&accum[c], v);
    }
}

__global__ void k_final(const double* __restrict__ accum, const float* __restrict__ b2,
                        float* __restrict__ out) {
    int t = threadIdx.x;
    if (t < F2) out[t] = (float)(accum[t] * (1.0 / (double)N_NODES)) + b2[t];
}

// ---------------- launch ----------------
extern "C" void kernel_launch(void* const* d_in, const int* in_sizes, int n_in,
                              void* d_out, int out_size, void* d_ws, size_t ws_size,
                              hipStream_t stream) {
    (void)in_sizes; (void)n_in; (void)out_size; (void)ws_size;
    const float* x   = (const float*)d_in[0];
    const int*   ei  = (const int*)d_in[1];
    const float* W1  = (const float*)d_in[2];
    const float* as1 = (const float*)d_in[3];
    const float* ad1 = (const float*)d_in[4];
    const float* b1  = (const float*)d_in[5];
    const float* W2  = (const float*)d_in[6];
    const float* as2 = (const float*)d_in[7];
    const float* ad2 = (const float*)d_in[8];
    const float* b2  = (const float*)d_in[9];
    float* out = (float*)d_out;

    char* ws = (char*)d_ws;
    size_t off = 0;
    auto alloc = [&](size_t bytes) -> void* {
        void* p = ws + off;
        off += (bytes + 255) & ~(size_t)255;
        return p;
    };
    unsigned char*  xw1f8 = (unsigned char*)alloc((size_t)(N_NODES + 1) * F1);
    float* h1       = (float*)alloc((size_t)N_NODES * F1 * 4);
    unsigned char*  xw2f8 = (unsigned char*)alloc((size_t)(N_NODES + 1) * F2);
    float* h2       = (float*)alloc((size_t)N_NODES * F2 * 4);
    unsigned short* w1t = (unsigned short*)alloc((size_t)F1 * F1 * 2);
    unsigned short* w2t = (unsigned short*)alloc((size_t)F2 * F1 * 2);
    float* a1s      = (float*)alloc((size_t)(N_NODES + 1) * H1 * 4);
    float* a1d      = (float*)alloc((size_t)N_NODES * H1 * 4);
    float* a2s      = (float*)alloc((size_t)(N_NODES + 1) * 4);
    float* a2d      = (float*)alloc((size_t)N_NODES * 4);
    int*   deg      = (int*)alloc((size_t)N_NODES * 4);
    unsigned* cbuf  = (unsigned*)alloc((size_t)TE * 4);
    int*   cnt      = (int*)alloc((size_t)NBINS * NBLK_A * 4);
    int*   btot     = (int*)alloc((size_t)NBINS * 4);
    int*   bstart   = (int*)alloc((size_t)(NBINS + 1) * 4);
    int*   rowstart = (int*)alloc((size_t)(N_NODES + 1) * 4);
    int*   csr      = (int*)alloc((size_t)TEP * 4);
    int*   incl     = (int*)alloc((size_t)N_NODES * 4);
    int*   bsum     = (int*)alloc(64 * 4);
    double* accum   = (double*)alloc(F2 * 8);

    const int nscan = (N_NODES + 1023) / 1024;  // 49
    const int nwave4 = (N_NODES + 3) / 4;       // 12500

    hipMemsetAsync(accum, 0, F2 * 8, stream);
    k_prep<<<96, 256, 0, stream>>>(W1, W2, w1t, w2t, a1s, a2s);
    k_l1_mm_hist<<<MM_BLOCKS + NBLK_A, 256, 0, stream>>>(x, w1t, as1, ad1, xw1f8, a1s, a1d, ei, cnt);
    k_btot<<<NBINS, 64, 0, stream>>>(cnt, btot);
    k_bstart<<<1, 64, 0, stream>>>(btot, bstart);
    k_scatter_coarse<<<NBLK_A, 256, 0, stream>>>(ei, cnt, bstart, cbuf);
    k_fine_hist<<<NBINS, 256, 0, stream>>>(cbuf, bstart, deg);
    k_scan1<<<nscan, 1024, 0, stream>>>(deg, incl, bsum);
    k_scan2<<<1, 64, 0, stream>>>(bsum, nscan);
    k_scan3<<<nscan, 1024, 0, stream>>>(incl, bsum, rowstart);
    k_build_csr<<<NBINS, 256, 0, stream>>>(cbuf, bstart, rowstart, deg, csr);
    k_l1_gather<<<nwave4, 256, 0, stream>>>(rowstart, csr, deg, a1s, a1d,
                                            (const unsigned*)xw1f8, b1, h1);
    k_l2_mm<<<MM_BLOCKS, 256, 0, stream>>>(h1, w2t, as2, ad2, xw2f8, a2s, a2d);
    k_l2_gather<<<nwave4, 256, 0, stream>>>(rowstart, csr, deg, a2s, a2d,
                                            (const unsigned*)xw2f8, h2);
    k_mean<<<MEAN_BLOCKS, 256, 0, stream>>>(h2, accum);
    k_final<<<1, 64, 0, stream>>>(accum, b2, out);
}

// Round 15
// 268.317 us; speedup vs baseline: 1.3640x; 1.0220x over previous
//
#include <hip/hip_runtime.h>
#include <math.h>

#define N_NODES 50000
#define SN      N_NODES               // sentinel node id for CSR pads
#define E_RAW   1600000
#define TE      (E_RAW + N_NODES)     // 1650000 edges incl. self loops
#define TEP     (TE + 16 * N_NODES)   // CSR padded to 16-aligned rows (upper bound)
#define F_IN    128
#define H1      4
#define F1      128                   // H1*C1
#define F2      64
#define NEG_SLOPE 0.2f
#define EPS_F   1e-16f
#define XPAD    136                   // LDS row stride in bf16 (kills bank conflicts)

// ---- bucket-sort CSR build params (all atomics are LDS-scope) ----
#define NBINS   196                   // coarse buckets: dst >> 8
#define NBLK_A  128                   // blocks in coarse hist/scatter
#define EPB     ((TE + NBLK_A - 1) / NBLK_A)
#define MM_BLOCKS (N_NODES / 16)      // 3125

__device__ __forceinline__ float lrelu(float v) { return v > 0.f ? v : NEG_SLOPE * v; }

typedef float vf2 __attribute__((ext_vector_type(2)));
typedef short short8 __attribute__((ext_vector_type(8)));
typedef float f32x4 __attribute__((ext_vector_type(4)));

__device__ __forceinline__ unsigned short f2bf(float f) {
    unsigned u = __float_as_uint(f);
    return (unsigned short)((u + 0x7fffu + ((u >> 16) & 1u)) >> 16);
}
__device__ __forceinline__ unsigned char f2fp8(float f) {
    int p = __builtin_amdgcn_cvt_pk_fp8_f32(f, f, 0, false);
    return (unsigned char)(p & 0xff);
}
__device__ __forceinline__ vf2 fp8lo(unsigned u) {   // bytes 0,1 -> 2 floats
    return __builtin_amdgcn_cvt_pk_f32_fp8((int)u, false);
}
__device__ __forceinline__ vf2 fp8hi(unsigned u) {   // bytes 2,3 -> 2 floats
    return __builtin_amdgcn_cvt_pk_f32_fp8((int)u, true);
}

// ---------------- prep: W -> transposed bf16 [c][k]; sentinel logits ---------
__global__ __launch_bounds__(256) void k_prep(const float* __restrict__ W1,
                                              const float* __restrict__ W2,
                                              unsigned short* __restrict__ w1t,
                                              unsigned short* __restrict__ w2t,
                                              float* __restrict__ a1s,
                                              float* __restrict__ a2s) {
    int idx = blockIdx.x * 256 + threadIdx.x;   // 96 blocks: 16384 + 8192
    if (idx < 16384) {
        int c = idx >> 7, k = idx & 127;
        w1t[idx] = f2bf(W1[k * F1 + c]);
    } else {
        int j = idx - 16384;
        int c = j >> 7, k = j & 127;
        w2t[j] = f2bf(W2[k * F2 + c]);
    }
    if (blockIdx.x == 0 && threadIdx.x < H1) a1s[SN * H1 + threadIdx.x] = -1e30f;
    if (blockIdx.x == 0 && threadIdx.x == H1) a2s[SN] = -1e30f;
}

// ---------------- layer1 matmul via MFMA (+ fused coarse histogram) ----------
__global__ __launch_bounds__(256) void k_l1_mm_hist(
    const float* __restrict__ x, const unsigned short* __restrict__ w1t,
    const float* __restrict__ atts, const float* __restrict__ attd,
    unsigned char* __restrict__ xwf8, float* __restrict__ a1s, float* __restrict__ a1d,
    const int* __restrict__ ei, int* __restrict__ cnt) {
    __shared__ __align__(16) unsigned short wls[F1 * XPAD];
    __shared__ __align__(16) unsigned short xs[16 * XPAD];
    const int t = threadIdx.x;
    if (blockIdx.x >= MM_BLOCKS) {
        int* hist = (int*)wls;
        const int blk = blockIdx.x - MM_BLOCKS;
        for (int i = t; i < NBINS; i += 256) hist[i] = 0;
        __syncthreads();
        const int e0 = blk * EPB, e1 = min(TE, e0 + EPB);
        for (int e = e0 + t; e < e1; e += 256) {
            int d = (e < E_RAW) ? ei[E_RAW + e] : (e - E_RAW);
            atomicAdd(&hist[d >> 8], 1);
        }
        __syncthreads();
        for (int i = t; i < NBINS; i += 256) cnt[i * NBLK_A + blk] = hist[i];
        return;
    }
    const int n0 = blockIdx.x * 16;
    {
        const float4* src = (const float4*)(x + (size_t)n0 * F_IN);
#pragma unroll
        for (int i = 0; i < 2; ++i) {
            int idx = t + 256 * i;
            float4 v = src[idx];
            int row = idx >> 5;
            int col = (idx & 31) * 4;
            ushort4 o = { f2bf(v.x), f2bf(v.y), f2bf(v.z), f2bf(v.w) };
            *(ushort4*)(xs + row * XPAD + col) = o;
        }
        const uint4* wsrc = (const uint4*)w1t;
#pragma unroll
        for (int i = 0; i < 8; ++i) {
            int idx = t + 256 * i;
            uint4 v = wsrc[idx];
            int row = idx >> 4;
            int col = (idx & 15) * 8;
            *(uint4*)(wls + row * XPAD + col) = v;
        }
    }
    __syncthreads();
    const int w = t >> 6;         // wave = head
    const int lane = t & 63;
    const int quad = lane >> 4;
    const int ncol = lane & 15;
    const int ch0 = w * 32;
    const unsigned short* arow = xs + ncol * XPAD;
    const unsigned short* brow0 = wls + (ch0 + ncol) * XPAD;
    const unsigned short* brow1 = brow0 + 16 * XPAD;
    f32x4 acc0 = {0.f, 0.f, 0.f, 0.f}, acc1 = {0.f, 0.f, 0.f, 0.f};
#pragma unroll
    for (int s = 0; s < 4; ++s) {
        int kb = s * 32 + quad * 8;
        short8 a  = *(const short8*)(arow + kb);
        short8 b0 = *(const short8*)(brow0 + kb);
        short8 b1 = *(const short8*)(brow1 + kb);
        acc0 = __builtin_amdgcn_mfma_f32_16x16x32_bf16(a, b0, acc0, 0, 0, 0);
        acc1 = __builtin_amdgcn_mfma_f32_16x16x32_bf16(a, b1, acc1, 0, 0, 0);
    }
    const int ch = ch0 + ncol;
    const float as0 = atts[ch], as1 = atts[ch + 16];
    const float ad0 = attd[ch], ad1 = attd[ch + 16];
#pragma unroll
    for (int reg = 0; reg < 4; ++reg) {
        const int n = n0 + quad * 4 + reg;
        float v0 = acc0[reg], v1 = acc1[reg];
        xwf8[(size_t)n * F1 + ch] = f2fp8(v0);
        xwf8[(size_t)n * F1 + ch + 16] = f2fp8(v1);
        float ps = fmaf(v0, as0, v1 * as1);
        float pd = fmaf(v0, ad0, v1 * ad1);
#pragma unroll
        for (int off = 1; off < 16; off <<= 1) {
            ps += __shfl_xor(ps, off);
            pd += __shfl_xor(pd, off);
        }
        if (ncol == 0) {
            a1s[n * H1 + w] = ps;
            a1d[n * H1 + w] = pd;
        }
    }
}

// ---------------- per-bin scan of cnt across blocks + bin totals -------------
__global__ __launch_bounds__(64) void k_btot(int* __restrict__ cnt, int* __restrict__ btot) {
    const int bin = blockIdx.x, lane = threadIdx.x;
    int c0 = cnt[bin * NBLK_A + 2 * lane];
    int c1 = cnt[bin * NBLK_A + 2 * lane + 1];
    int s = c0 + c1;
    int incl = s;
#pragma unroll
    for (int off = 1; off < 64; off <<= 1) {
        int u = __shfl_up(incl, off, 64);
        if (lane >= off) incl += u;
    }
    int excl = incl - s;
    cnt[bin * NBLK_A + 2 * lane] = excl;
    cnt[bin * NBLK_A + 2 * lane + 1] = excl + c0;
    if (lane == 63) btot[bin] = incl;
}

// ---------------- exclusive scan of 196 bin totals -> bucket_start -----------
__global__ __launch_bounds__(64) void k_bstart(const int* __restrict__ btot,
                                               int* __restrict__ bstart) {
    const int lane = threadIdx.x;
    int v[4]; int s = 0;
#pragma unroll
    for (int j = 0; j < 4; ++j) {
        int i = 4 * lane + j;
        v[j] = (i < NBINS) ? btot[i] : 0;
        s += v[j];
    }
    int incl = s;
#pragma unroll
    for (int off = 1; off < 64; off <<= 1) {
        int u = __shfl_up(incl, off, 64);
        if (lane >= off) incl += u;
    }
    int run = incl - s;
#pragma unroll
    for (int j = 0; j < 4; ++j) {
        int i = 4 * lane + j;
        if (i < NBINS) bstart[i] = run;
        run += v[j];
    }
    if (lane == 63) bstart[NBINS] = TE;
}

// ---------------- scatter into coarse buckets (plain stores) -----------------
__global__ __launch_bounds__(256) void k_scatter_coarse(const int* __restrict__ ei,
                                                        const int* __restrict__ cnt,
                                                        const int* __restrict__ bstart,
                                                        unsigned* __restrict__ cbuf) {
    __shared__ int cur[NBINS];
    const int t = threadIdx.x, blk = blockIdx.x;
    for (int i = t; i < NBINS; i += 256) cur[i] = cnt[i * NBLK_A + blk] + bstart[i];
    __syncthreads();
    const int e0 = blk * EPB, e1 = min(TE, e0 + EPB);
    for (int e = e0 + t; e < e1; e += 256) {
        int s, d;
        if (e < E_RAW) { s = ei[e]; d = ei[E_RAW + e]; }
        else { s = e - E_RAW; d = s; }
        int pos = atomicAdd(&cur[d >> 8], 1);   // LDS atomic
        cbuf[pos] = ((unsigned)(d & 255) << 16) | (unsigned)s;
    }
}

// ---------------- fine histogram -> deg --------------------
__global__ __launch_bounds__(256) void k_fine_hist(const unsigned* __restrict__ cbuf,
                                                   const int* __restrict__ bstart,
                                                   int* __restrict__ deg) {
    __shared__ int hist[256];
    const int t = threadIdx.x, b = blockIdx.x;
    hist[t] = 0;
    __syncthreads();
    const int i0 = bstart[b], i1 = bstart[b + 1];
    for (int i = i0 + t; i < i1; i += 256) atomicAdd(&hist[cbuf[i] >> 16], 1);
    __syncthreads();
    const int d = b * 256 + t;
    if (d < N_NODES) deg[d] = hist[t];
}

// ---------------- exclusive scan over 16-PADDED degrees (2-level) ------------
__global__ __launch_bounds__(1024) void k_scan1(const int* __restrict__ deg,
                                                int* __restrict__ incl, int* __restrict__ bsum) {
    int t = threadIdx.x, g = blockIdx.x;
    int idx = g * 1024 + t;
    int v = (idx < N_NODES) ? ((deg[idx] + 15) & ~15) : 0;
    int lane = t & 63, w = t >> 6;
#pragma unroll
    for (int off = 1; off < 64; off <<= 1) {
        int u = __shfl_up(v, off, 64);
        if (lane >= off) v += u;
    }
    __shared__ int ws[16];
    if (lane == 63) ws[w] = v;
    __syncthreads();
    if (w == 0 && lane < 16) {
        int s = ws[lane];
#pragma unroll
        for (int off = 1; off < 16; off <<= 1) {
            int u = __shfl_up(s, off, 16);
            if (lane >= off) s += u;
        }
        ws[lane] = s;
    }
    __syncthreads();
    if (w > 0) v += ws[w - 1];
    if (idx < N_NODES) incl[idx] = v;
    if (t == 1023) bsum[g] = v;
}

__global__ void k_scan2(int* __restrict__ bsum, int nblk) {
    int t = threadIdx.x;
    int v = (t < nblk) ? bsum[t] : 0;
#pragma unroll
    for (int off = 1; off < 64; off <<= 1) {
        int u = __shfl_up(v, off, 64);
        if (t >= off) v += u;
    }
    if (t < nblk) bsum[t] = v;
}

__global__ __launch_bounds__(1024) void k_scan3(const int* __restrict__ incl,
                                                const int* __restrict__ bsum,
                                                int* __restrict__ rowstart) {
    int idx = blockIdx.x * 1024 + threadIdx.x;
    if (idx >= N_NODES) return;
    int off = (blockIdx.x > 0) ? bsum[blockIdx.x - 1] : 0;
    rowstart[idx + 1] = incl[idx] + off;
    if (idx == 0) rowstart[0] = 0;
}

// ---------------- per-bucket scatter into csr + sentinel pad fill ------------
__global__ __launch_bounds__(256) void k_build_csr(const unsigned* __restrict__ cbuf,
                                                   const int* __restrict__ bstart,
                                                   const int* __restrict__ rowstart,
                                                   const int* __restrict__ deg,
                                                   int* __restrict__ csr) {
    __shared__ int cur[256];
    const int t = threadIdx.x, b = blockIdx.x;
    const int d = b * 256 + t;
    cur[t] = (d < N_NODES) ? rowstart[d] : 0;
    __syncthreads();
    const int i0 = bstart[b], i1 = bstart[b + 1];
    for (int i = i0 + t; i < i1; i += 256) {
        unsigned v = cbuf[i];
        int pos = atomicAdd(&cur[v >> 16], 1);   // LDS atomic
        csr[pos] = (int)(v & 0xffffu);
    }
    __syncthreads();
    if (d < N_NODES) {
        const int pend = rowstart[d] + ((deg[d] + 15) & ~15);
        for (int i = cur[t]; i < pend; ++i) csr[i] = SN;
    }
}

// ---------------- layer1 gather: shuffle-shared weights, 16 edges/iter -------
// Round-14 lesson: inlined weights made every 8-lane octet redundantly compute
// the same 8 exps (VALUBusy 87%). Now each lane computes EXACTLY ONE weight
// (edge = half*8+(sub&7), its own head h) and octets share via 8 __shfl
// (ds_bpermute) — weight values bitwise identical, 1/8 the exp+a1s-gather work.
__global__ __launch_bounds__(256) void k_l1_gather(
    const int* __restrict__ rowstart, const int* __restrict__ csr,
    const int* __restrict__ deg, const float* __restrict__ a1s,
    const float* __restrict__ a1d, const unsigned* __restrict__ xwu,
    const float* __restrict__ b1, float* __restrict__ h1) {
    const int lane = threadIdx.x & 63;
    const int wid = threadIdx.x >> 6;
    const int n = blockIdx.x * 4 + wid;
    if (n >= N_NODES) return;
    const int rs = rowstart[n];
    const int nb16 = (deg[n] + 15) >> 4;
    const int half = lane >> 5;
    const int sub = lane & 31;          // channel group 4*sub..4*sub+3
    const int h = sub >> 3;             // head
    const float adh = a1d[n * H1 + h];
    const int4* c4 = (const int4*)(csr + rs);
    const int eoff = half * 8 + (sub & 7);      // this lane's weight-edge in block
    const int wbase = half * 32 + (h << 3);     // octet's shuffle source base
    float den = 0.f, f0 = 0.f, f1 = 0.f, f2 = 0.f, f3 = 0.f;
    for (int b = 0; b < nb16; ++b) {
        const int i0 = 4 * b + 2 * half;
        int4 sA = c4[i0], sB = c4[i0 + 1];
        int se = csr[rs + 16 * b + eoff];
        unsigned u0 = xwu[sA.x * 32 + sub], u1 = xwu[sA.y * 32 + sub];
        unsigned u2 = xwu[sA.z * 32 + sub], u3 = xwu[sA.w * 32 + sub];
        unsigned u4 = xwu[sB.x * 32 + sub], u5 = xwu[sB.y * 32 + sub];
        unsigned u6 = xwu[sB.z * 32 + sub], u7 = xwu[sB.w * 32 + sub];
        float we = __expf(lrelu(a1s[se * H1 + h] + adh));
        float w0 = __shfl(we, wbase + 0), w1 = __shfl(we, wbase + 1);
        float w2 = __shfl(we, wbase + 2), w3 = __shfl(we, wbase + 3);
        float w4 = __shfl(we, wbase + 4), w5 = __shfl(we, wbase + 5);
        float w6 = __shfl(we, wbase + 6), w7 = __shfl(we, wbase + 7);
        den += ((w0 + w1) + (w2 + w3)) + ((w4 + w5) + (w6 + w7));
        vf2 l0 = fp8lo(u0), v0 = fp8hi(u0);
        f0 = fmaf(w0, l0.x, f0); f1 = fmaf(w0, l0.y, f1);
        f2 = fmaf(w0, v0.x, f2); f3 = fmaf(w0, v0.y, f3);
        vf2 l1 = fp8lo(u1), v1 = fp8hi(u1);
        f0 = fmaf(w1, l1.x, f0); f1 = fmaf(w1, l1.y, f1);
        f2 = fmaf(w1, v1.x, f2); f3 = fmaf(w1, v1.y, f3);
        vf2 l2 = fp8lo(u2), v2 = fp8hi(u2);
        f0 = fmaf(w2, l2.x, f0); f1 = fmaf(w2, l2.y, f1);
        f2 = fmaf(w2, v2.x, f2); f3 = fmaf(w2, v2.y, f3);
        vf2 l3 = fp8lo(u3), v3 = fp8hi(u3);
        f0 = fmaf(w3, l3.x, f0); f1 = fmaf(w3, l3.y, f1);
        f2 = fmaf(w3, v3.x, f2); f3 = fmaf(w3, v3.y, f3);
        vf2 l4 = fp8lo(u4), v4 = fp8hi(u4);
        f0 = fmaf(w4, l4.x, f0); f1 = fmaf(w4, l4.y, f1);
        f2 = fmaf(w4, v4.x, f2); f3 = fmaf(w4, v4.y, f3);
        vf2 l5 = fp8lo(u5), v5 = fp8hi(u5);
        f0 = fmaf(w5, l5.x, f0); f1 = fmaf(w5, l5.y, f1);
        f2 = fmaf(w5, v5.x, f2); f3 = fmaf(w5, v5.y, f3);
        vf2 l6 = fp8lo(u6), v6 = fp8hi(u6);
        f0 = fmaf(w6, l6.x, f0); f1 = fmaf(w6, l6.y, f1);
        f2 = fmaf(w6, v6.x, f2); f3 = fmaf(w6, v6.y, f3);
        vf2 l7 = fp8lo(u7), v7 = fp8hi(u7);
        f0 = fmaf(w7, l7.x, f0); f1 = fmaf(w7, l7.y, f1);
        f2 = fmaf(w7, v7.x, f2); f3 = fmaf(w7, v7.y, f3);
    }
    f0 += __shfl_xor(f0, 32);
    f1 += __shfl_xor(f1, 32);
    f2 += __shfl_xor(f2, 32);
    f3 += __shfl_xor(f3, 32);
    den += __shfl_xor(den, 32);
    if (half == 0) {
        const float inv = 1.f / (den + EPS_F);
        float4 bb = ((const float4*)b1)[sub];
        float o0 = fmaf(f0, inv, bb.x);
        float o1 = fmaf(f1, inv, bb.y);
        float o2 = fmaf(f2, inv, bb.z);
        float o3 = fmaf(f3, inv, bb.w);
        o0 = o0 > 0.f ? o0 : expm1f(o0);
        o1 = o1 > 0.f ? o1 : expm1f(o1);
        o2 = o2 > 0.f ? o2 : expm1f(o2);
        o3 = o3 > 0.f ? o3 : expm1f(o3);
        ((float4*)h1)[(size_t)n * 32 + sub] = make_float4(o0, o1, o2, o3);
    }
}

// ---------------- layer2 matmul via MFMA (fp8 out, single head) --------------
__global__ __launch_bounds__(256) void k_l2_mm(
    const float* __restrict__ h1, const unsigned short* __restrict__ w2t,
    const float* __restrict__ atts, const float* __restrict__ attd,
    unsigned char* __restrict__ xwf8, float* __restrict__ a2s, float* __restrict__ a2d) {
    __shared__ __align__(16) unsigned short wls[F2 * XPAD];
    __shared__ __align__(16) unsigned short xs[16 * XPAD];
    __shared__ float parts[16][4], partd[16][4];
    const int t = threadIdx.x;
    const int n0 = blockIdx.x * 16;
    {
        const float4* src = (const float4*)(h1 + (size_t)n0 * F1);
#pragma unroll
        for (int i = 0; i < 2; ++i) {
            int idx = t + 256 * i;
            float4 v = src[idx];
            int row = idx >> 5;
            int col = (idx & 31) * 4;
            ushort4 o = { f2bf(v.x), f2bf(v.y), f2bf(v.z), f2bf(v.w) };
            *(ushort4*)(xs + row * XPAD + col) = o;
        }
        const uint4* wsrc = (const uint4*)w2t;
#pragma unroll
        for (int i = 0; i < 4; ++i) {
            int idx = t + 256 * i;
            uint4 v = wsrc[idx];
            int row = idx >> 4;
            int col = (idx & 15) * 8;
            *(uint4*)(wls + row * XPAD + col) = v;
        }
    }
    __syncthreads();
    const int w = t >> 6;
    const int lane = t & 63;
    const int quad = lane >> 4;
    const int ncol = lane & 15;
    const int ch0 = w * 16;
    const unsigned short* arow = xs + ncol * XPAD;
    const unsigned short* brow = wls + (ch0 + ncol) * XPAD;
    f32x4 acc = {0.f, 0.f, 0.f, 0.f};
#pragma unroll
    for (int s = 0; s < 4; ++s) {
        int kb = s * 32 + quad * 8;
        short8 a = *(const short8*)(arow + kb);
        short8 b = *(const short8*)(brow + kb);
        acc = __builtin_amdgcn_mfma_f32_16x16x32_bf16(a, b, acc, 0, 0, 0);
    }
    const int ch = ch0 + ncol;
    const float asv = atts[ch], adv = attd[ch];
#pragma unroll
    for (int reg = 0; reg < 4; ++reg) {
        const int m = quad * 4 + reg;
        float v = acc[reg];
        xwf8[(size_t)(n0 + m) * F2 + ch] = f2fp8(v);
        float ps = v * asv, pd = v * adv;
#pragma unroll
        for (int off = 1; off < 16; off <<= 1) {
            ps += __shfl_xor(ps, off);
            pd += __shfl_xor(pd, off);
        }
        if (ncol == 0) { parts[m][w] = ps; partd[m][w] = pd; }
    }
    __syncthreads();
    if (t < 16) {
        a2s[n0 + t] = (parts[t][0] + parts[t][1]) + (parts[t][2] + parts[t][3]);
        a2d[n0 + t] = (partd[t][0] + partd[t][1]) + (partd[t][2] + partd[t][3]);
    }
}

// ---------------- layer2 gather: shuffle-shared weights, 16 edges/iter -------
// Quarter q handles contiguous edges 4q..4q+3 (one int4 load). Each lane
// computes the weight for edge lane&15; quarters fetch theirs via __shfl.
__global__ __launch_bounds__(256) void k_l2_gather(
    const int* __restrict__ rowstart, const int* __restrict__ csr,
    const int* __restrict__ deg, const float* __restrict__ a2s,
    const float* __restrict__ a2d, const unsigned* __restrict__ xwu,
    float* __restrict__ h2) {
    const int lane = threadIdx.x & 63;
    const int wid = threadIdx.x >> 6;
    const int n = blockIdx.x * 4 + wid;
    if (n >= N_NODES) return;
    const int rs = rowstart[n];
    const int nb16 = (deg[n] + 15) >> 4;
    const int q = lane >> 4;
    const int sub = lane & 15;          // channel group 4*sub..4*sub+3
    const float adv = a2d[n];
    const int4* c4 = (const int4*)(csr + rs);
    float den = 0.f, f0 = 0.f, f1 = 0.f, f2 = 0.f, f3 = 0.f;
    for (int b = 0; b < nb16; ++b) {
        int4 s4 = c4[4 * b + q];                 // edges 4q..4q+3
        int se = csr[rs + 16 * b + sub];         // weight edge = sub
        unsigned u0 = xwu[s4.x * 16 + sub], u1 = xwu[s4.y * 16 + sub];
        unsigned u2 = xwu[s4.z * 16 + sub], u3 = xwu[s4.w * 16 + sub];
        float we = __expf(lrelu(a2s[se] + adv));
        float w0 = __shfl(we, 4 * q + 0), w1 = __shfl(we, 4 * q + 1);
        float w2 = __shfl(we, 4 * q + 2), w3 = __shfl(we, 4 * q + 3);
        den += (w0 + w1) + (w2 + w3);
        vf2 l0 = fp8lo(u0), v0 = fp8hi(u0);
        f0 = fmaf(w0, l0.x, f0); f1 = fmaf(w0, l0.y, f1);
        f2 = fmaf(w0, v0.x, f2); f3 = fmaf(w0, v0.y, f3);
        vf2 l1 = fp8lo(u1), v1 = fp8hi(u1);
        f0 = fmaf(w1, l1.x, f0); f1 = fmaf(w1, l1.y, f1);
        f2 = fmaf(w1, v1.x, f2); f3 = fmaf(w1, v1.y, f3);
        vf2 l2 = fp8lo(u2), v2 = fp8hi(u2);
        f0 = fmaf(w2, l2.x, f0); f1 = fmaf(w2, l2.y, f1);
        f2 = fmaf(w2, v2.x, f2); f3 = fmaf(w2, v2.y, f3);
        vf2 l3 = fp8lo(u3), v3 = fp8hi(u3);
        f0 = fmaf(w3, l3.x, f0); f1 = fmaf(w3, l3.y, f1);
        f2 = fmaf(w3, v3.x, f2); f3 = fmaf(w3, v3.y, f3);
    }
#pragma unroll
    for (int off = 16; off <= 32; off <<= 1) {
        f0 += __shfl_xor(f0, off);
        f1 += __shfl_xor(f1, off);
        f2 += __shfl_xor(f2, off);
        f3 += __shfl_xor(f3, off);
        den += __shfl_xor(den, off);
    }
    if (lane < 16) {
        const float inv = 1.f / (den + EPS_F);
        ((float4*)h2)[(size_t)n * 16 + sub] =
            make_float4(f0 * inv, f1 * inv, f2 * inv, f3 * inv);
    }
}

// ---------------- mean over nodes (fp64 accum) ----------------
#define MEAN_BLOCKS 256
__global__ __launch_bounds__(256) void k_mean(const float* __restrict__ h2,
                                              double* __restrict__ accum) {
    const int t = threadIdx.x;
    const int c = t & 63;
    double acc = 0.0;
    const size_t total = (size_t)N_NODES * F2;
    for (size_t idx = (size_t)blockIdx.x * 256 + t; idx < total; idx += (size_t)MEAN_BLOCKS * 256)
        acc += (double)h2[idx];
    __shared__ double red[256];
    red[t] = acc;
    __syncthreads();
    if (t < 64) {
        double v = red[t] + red[t + 64] + red[t + 128] + red[t + 192];
        atomicAdd(&accum[c], v);
    }
}

__global__ void k_final(const double* __restrict__ accum, const float* __restrict__ b2,
                        float* __restrict__ out) {
    int t = threadIdx.x;
    if (t < F2) out[t] = (float)(accum[t] * (1.0 / (double)N_NODES)) + b2[t];
}

// ---------------- launch ----------------
extern "C" void kernel_launch(void* const* d_in, const int* in_sizes, int n_in,
                              void* d_out, int out_size, void* d_ws, size_t ws_size,
                              hipStream_t stream) {
    (void)in_sizes; (void)n_in; (void)out_size; (void)ws_size;
    const float* x   = (const float*)d_in[0];
    const int*   ei  = (const int*)d_in[1];
    const float* W1  = (const float*)d_in[2];
    const float* as1 = (const float*)d_in[3];
    const float* ad1 = (const float*)d_in[4];
    const float* b1  = (const float*)d_in[5];
    const float* W2  = (const float*)d_in[6];
    const float* as2 = (const float*)d_in[7];
    const float* ad2 = (const float*)d_in[8];
    const float* b2  = (const float*)d_in[9];
    float* out = (float*)d_out;

    char* ws = (char*)d_ws;
    size_t off = 0;
    auto alloc = [&](size_t bytes) -> void* {
        void* p = ws + off;
        off += (bytes + 255) & ~(size_t)255;
        return p;
    };
    unsigned char*  xw1f8 = (unsigned char*)alloc((size_t)(N_NODES + 1) * F1);
    float* h1       = (float*)alloc((size_t)N_NODES * F1 * 4);
    unsigned char*  xw2f8 = (unsigned char*)alloc((size_t)(N_NODES + 1) * F2);
    float* h2       = (float*)alloc((size_t)N_NODES * F2 * 4);
    unsigned short* w1t = (unsigned short*)alloc((size_t)F1 * F1 * 2);
    unsigned short* w2t = (unsigned short*)alloc((size_t)F2 * F1 * 2);
    float* a1s      = (float*)alloc((size_t)(N_NODES + 1) * H1 * 4);
    float* a1d      = (float*)alloc((size_t)N_NODES * H1 * 4);
    float* a2s      = (float*)alloc((size_t)(N_NODES + 1) * 4);
    float* a2d      = (float*)alloc((size_t)N_NODES * 4);
    int*   deg      = (int*)alloc((size_t)N_NODES * 4);
    unsigned* cbuf  = (unsigned*)alloc((size_t)TE * 4);
    int*   cnt      = (int*)alloc((size_t)NBINS * NBLK_A * 4);
    int*   btot     = (int*)alloc((size_t)NBINS * 4);
    int*   bstart   = (int*)alloc((size_t)(NBINS + 1) * 4);
    int*   rowstart = (int*)alloc((size_t)(N_NODES + 1) * 4);
    int*   csr      = (int*)alloc((size_t)TEP * 4);
    int*   incl     = (int*)alloc((size_t)N_NODES * 4);
    int*   bsum     = (int*)alloc(64 * 4);
    double* accum   = (double*)alloc(F2 * 8);

    const int nscan = (N_NODES + 1023) / 1024;  // 49
    const int nwave4 = (N_NODES + 3) / 4;       // 12500

    hipMemsetAsync(accum, 0, F2 * 8, stream);
    k_prep<<<96, 256, 0, stream>>>(W1, W2, w1t, w2t, a1s, a2s);
    k_l1_mm_hist<<<MM_BLOCKS + NBLK_A, 256, 0, stream>>>(x, w1t, as1, ad1, xw1f8, a1s, a1d, ei, cnt);
    k_btot<<<NBINS, 64, 0, stream>>>(cnt, btot);
    k_bstart<<<1, 64, 0, stream>>>(btot, bstart);
    k_scatter_coarse<<<NBLK_A, 256, 0, stream>>>(ei, cnt, bstart, cbuf);
    k_fine_hist<<<NBINS, 256, 0, stream>>>(cbuf, bstart, deg);
    k_scan1<<<nscan, 1024, 0, stream>>>(deg, incl, bsum);
    k_scan2<<<1, 64, 0, stream>>>(bsum, nscan);
    k_scan3<<<nscan, 1024, 0, stream>>>(incl, bsum, rowstart);
    k_build_csr<<<NBINS, 256, 0, stream>>>(cbuf, bstart, rowstart, deg, csr);
    k_l1_gather<<<nwave4, 256, 0, stream>>>(rowstart, csr, deg, a1s, a1d,
                                            (const unsigned*)xw1f8, b1, h1);
    k_l2_mm<<<MM_BLOCKS, 256, 0, stream>>>(h1, w2t, as2, ad2, xw2f8, a2s, a2d);
    k_l2_gather<<<nwave4, 256, 0, stream>>>(rowstart, csr, deg, a2s, a2d,
                                            (const unsigned*)xw2f8, h2);
    k_mean<<<MEAN_BLOCKS, 256, 0, stream>>>(h2, accum);
    k_final<<<1, 64, 0, stream>>>(accum, b2, out);
}